// Round 1
// baseline (210.418 us; speedup 1.0000x reference)
//
#include <hip/hip_runtime.h>
#include <hip/hip_bf16.h>
#include <math.h>

// Problem constants
#define L_SEQ   1024
#define NB      8
#define H_DIM   300
#define KWIN    5
#define NREL    11          // 2K+1
#define PDIM    50
#define NC      11234       // band pair count for L=1024, K=5
#define BNC     (NB*NC)     // 89872
#define LN_EPS  1e-5f

#define KPAD    320         // K padded with zeros in [300,320)
#define WKSTR   320         // Wb k-stride (shorts)
#define WNPAD   320         // Wb padded n rows

#define ITILE   8           // i rows per block
#define HROWS   18          // hc halo rows: i0-5 .. i0+12
#define ZROW    46          // zero row used for MFMA clamp (rows 46..47 zero)
#define XROWS   48          // 0..7 he/Ae, 8..15 zero, 16..33 hc/Ac,
                            // 34..44 Pb, 45 ones, 46..47 zero
#define XSTR    328         // X row stride in shorts
#define GSTR2   32          // GL row stride (floats); stores G cols 16..45
#define NPAIR   (ITILE*NREL)  // 88

// Workspace layout (float offsets)
#define WB_OFF   2048       // prelbf (11*328 shorts = 7216 B) lives at 0
                            // Wb: 2*320*320 shorts = 102400 floats

typedef __attribute__((ext_vector_type(8))) short s16x8;
typedef __attribute__((ext_vector_type(4))) short s16x4;
typedef __attribute__((ext_vector_type(4))) float f32x4;

__device__ __forceinline__ short f2bf(float f) {
    unsigned u = __float_as_uint(f);
    u += 0x7fffu + ((u >> 16) & 1u);
    return (short)(u >> 16);
}
__device__ __forceinline__ float bf2f(short s) {
    return __uint_as_float(((unsigned)(unsigned short)s) << 16);
}

// band row start: first linear index n of row i
__device__ __forceinline__ int rowstart(int i) {
    if (i < 5)     return 6 * i + (i * (i - 1)) / 2;
    if (i <= 1018) return 40 + (i - 5) * 11;
    int d = i - 1019;
    return 11194 + d * 10 - (d * (d - 1)) / 2;
}

// ---------------------------------------------------------------------------
// Kernel 1: prep (unchanged).
//  blocks 0..14   : prelbf[r][h] = bf16(b1[h] + sum_d W1[h][600+d]*emb11[r][d]),
//                   stride 328, zero pad h>=300
//  blocks 15..814 : Wb[z][n][k] = bf16(W1[n][z*300+k]), zero-padded
__global__ __launch_bounds__(256) void prep_kernel(
    const float* __restrict__ pos_W, const float* __restrict__ W1,
    const float* __restrict__ b1, short* __restrict__ prelbf,
    short* __restrict__ Wb)
{
    if (blockIdx.x < 15) {
        __shared__ float semb[NREL * PDIM];
        for (int t = threadIdx.x; t < NREL * PDIM; t += 256) {
            int r = t / PDIM, d = t % PDIM;
            float acc = 0.f;
#pragma unroll
            for (int r2 = 0; r2 < NREL; ++r2) {
                float cnt = (float)(L_SEQ - abs(r2 - KWIN));
                int dr = r - r2;
                acc += cnt * expf(-(float)(dr * dr)) * pos_W[r2 * PDIM + d];
            }
            semb[t] = acc;
        }
        __syncthreads();
        int t = blockIdx.x * 256 + threadIdx.x;
        if (t < NREL * XSTR) {
            int r = t / XSTR, h = t % XSTR;
            float acc = 0.f;
            if (h < H_DIM) {
                acc = b1[h];
                const float* wrow = W1 + (size_t)h * 650 + 600;
                const float* em = semb + r * PDIM;
#pragma unroll 10
                for (int d = 0; d < PDIM; ++d) acc += wrow[d] * em[d];
            }
            prelbf[t] = (h < H_DIM) ? f2bf(acc) : (short)0;
        }
    } else {
        int id = (blockIdx.x - 15) * 256 + threadIdx.x;
        if (id < 2 * WNPAD * WKSTR) {
            int z = id / (WNPAD * WKSTR);
            int rem = id % (WNPAD * WKSTR);
            int n = rem / WKSTR, k = rem % WKSTR;
            float v = (n < H_DIM && k < H_DIM) ? W1[(size_t)n * 650 + z * H_DIM + k] : 0.f;
            Wb[id] = f2bf(v);
        }
    }
}

// ---------------------------------------------------------------------------
// Kernel 2: fused GEMM + Gram mini-GEMM + epilogue.
// Block = (b, i-tile of 8), 512 threads (8 waves), grid 1024.
// LDS ~37.7 KB -> 4 blocks/CU; launch_bounds(512,8) caps VGPR at 64 so the
// CU runs 32 waves (100% theoretical occupancy).
__global__ __launch_bounds__(512, 8) void fused_kernel(
    const float* __restrict__ h_e, const float* __restrict__ h_c,
    const float* __restrict__ h_share, const short* __restrict__ Wb,
    const short* __restrict__ prelbf,
    const float* __restrict__ ln_g, const float* __restrict__ ln_b,
    const float* __restrict__ W2, const float* __restrict__ b2,
    float* __restrict__ out, float* __restrict__ posout)
{
    __shared__ __align__(16) short X[XROWS * XSTR];    // 31488 B
    __shared__ __align__(16) float GL[XROWS * GSTR2];  // 6144 B
    __shared__ __align__(16) float gdiag[8];           // SSe (diag rows 0..7)

    const int tid = threadIdx.x;
    const int b   = blockIdx.x >> 7;          // 128 i-tiles per batch
    const int i0  = (blockIdx.x & 127) * ITILE;

    // ---- zero-fill: rows 8..15 & 46..47 full width (10*41 chunks) + rows
    // 0..7,16..33 cols [304,328) (26*3 chunks) = 488 16B chunks
    for (int t = tid; t < 488; t += 512) {
        int row, c;
        if (t < 410) { int rr2 = t / 41; row = rr2 < 8 ? 8 + rr2 : 46 + (rr2 - 8); c = (t % 41) * 8; }
        else         { int u = t - 410; int r = u / 3; row = r < 8 ? r : 8 + r; c = 304 + (u % 3) * 8; }
        *(s16x8*)&X[row * XSTR + c] = (s16x8){0,0,0,0,0,0,0,0};
    }
    // ---- ones row (45): bf16(1.0)=0x3F80 for cols<300, else 0
    for (int t = tid; t < XSTR; t += 512)
        X[45 * XSTR + t] = (t < H_DIM) ? (short)0x3F80 : (short)0;
    // ---- Pb rows 34..44: straight copy from prelbf (layout matches)
    for (int t = tid; t < NREL * 41; t += 512) {
        int r = t / 41, c = (t % 41) * 8;
        *(s16x8*)&X[(34 + r) * XSTR + c] = *(const s16x8*)(prelbf + r * XSTR + c);
    }
    // ---- stage 18 halo rows; h_share read once per row.
    for (int t = tid; t < HROWS * 76; t += 512) {
        int s = t / 76, kc = (t % 76) * 4;
        int g = i0 - KWIN + s;
        bool valid = (kc < H_DIM) && (g >= 0) && (g < L_SEQ);
        float4 hs4 = make_float4(0.f,0.f,0.f,0.f), hc4 = hs4;
        size_t off = 0;
        if (valid) {
            off = ((size_t)b * L_SEQ + g) * H_DIM + kc;
            hs4 = *(const float4*)(h_share + off);
            hc4 = *(const float4*)(h_c + off);
        }
        s16x4 vc = { f2bf(hc4.x + hs4.x), f2bf(hc4.y + hs4.y),
                     f2bf(hc4.z + hs4.z), f2bf(hc4.w + hs4.w) };
        *(s16x4*)&X[(16 + s) * XSTR + kc] = vc;
        if (s >= KWIN && s < KWIN + ITILE) {   // he row: g = i0 + (s-5)
            float4 he4 = make_float4(0.f,0.f,0.f,0.f);
            if (valid) he4 = *(const float4*)(h_e + off);
            s16x4 ve = { f2bf(he4.x + hs4.x), f2bf(he4.y + hs4.y),
                         f2bf(he4.z + hs4.z), f2bf(he4.w + hs4.w) };
            *(s16x4*)&X[(s - KWIN) * XSTR + kc] = ve;
        }
    }
    __syncthreads();

    // ---- Main GEMM. 8 waves: wz = wave>>2 (0: rows 0..15 with W1e,
    // 1: rows 16..31 + rows 32..33-clamped with W1c), nsl = (wave&3)*80.
    const int wave = tid >> 6, lane = tid & 63;
    const int fr = lane & 15, fq = lane >> 4;
    const int wz  = wave >> 2;
    const int nsl = (wave & 3) * 80;
    const short* wbase = Wb + ((size_t)(wz * WNPAD + nsl + fr)) * WKSTR + fq * 8;

    const int mrow0 = wz ? (16 + fr) : fr;
    const int mrow1 = (fr < 2) ? (32 + fr) : ZROW;   // wz==1 only

    f32x4 acc0[5] = {};
    f32x4 acc1[5] = {};

    for (int k0 = 0; k0 < KPAD; k0 += 32) {
        s16x8 bf[5];
#pragma unroll
        for (int nt = 0; nt < 5; ++nt)
            bf[nt] = *(const s16x8*)(wbase + (size_t)nt * 16 * WKSTR + k0);
        s16x8 af0 = *(const s16x8*)&X[mrow0 * XSTR + k0 + fq * 8];
#pragma unroll
        for (int nt = 0; nt < 5; ++nt)
            acc0[nt] = __builtin_amdgcn_mfma_f32_16x16x32_bf16(af0, bf[nt], acc0[nt], 0, 0, 0);
        if (wz) {
            s16x8 af1 = *(const s16x8*)&X[mrow1 * XSTR + k0 + fq * 8];
#pragma unroll
            for (int nt = 0; nt < 5; ++nt)
                acc1[nt] = __builtin_amdgcn_mfma_f32_16x16x32_bf16(af1, bf[nt], acc1[nt], 0, 0, 0);
        }
    }
    __syncthreads();   // all waves done reading X inputs

    // ---- write Ae/Ac into X (bf16). C/D: col = nsl+nt*16+fr, row = fq*4+r2
#pragma unroll
    for (int nt = 0; nt < 5; ++nt) {
        const int col = nsl + nt * 16 + fr;     // cols>=300 compute to 0
        if (!wz) {
#pragma unroll
            for (int r2 = 0; r2 < 4; ++r2)
                X[(fq * 4 + r2) * XSTR + col] = f2bf(acc0[nt][r2]);
        } else {
#pragma unroll
            for (int r2 = 0; r2 < 4; ++r2)
                X[(16 + fq * 4 + r2) * XSTR + col] = f2bf(acc0[nt][r2]);
#pragma unroll
            for (int r2 = 0; r2 < 4; ++r2) {
                int rw = 32 + fq * 4 + r2;
                if (rw < 34) X[rw * XSTR + col] = f2bf(acc1[nt][r2]);
            }
        }
    }
    __syncthreads();

    // ---- Gram mini-GEMM: upper triangle of the 3x3 fragment grid over 48
    // rows (k = 320). Waves 0..5 -> frags (0,0),(0,1),(0,2),(1,1),(1,2),(2,2).
    // Only cols 16..45 are ever read -> compact store (col-16); diag of frag
    // (0,0) stashed separately for SSe.
    if (wave < 6) {
        const int mf = (wave < 3) ? 0 : (wave < 5 ? 1 : 2);
        const int nf = (wave < 3) ? wave : (wave < 5 ? wave - 2 : 2);
        f32x4 ga = {};
        for (int k0 = 0; k0 < KPAD; k0 += 32) {
            s16x8 av = *(const s16x8*)&X[(mf * 16 + fr) * XSTR + k0 + fq * 8];
            s16x8 bv = *(const s16x8*)&X[(nf * 16 + fr) * XSTR + k0 + fq * 8];
            ga = __builtin_amdgcn_mfma_f32_16x16x32_bf16(av, bv, ga, 0, 0, 0);
        }
#pragma unroll
        for (int r2 = 0; r2 < 4; ++r2) {
            const int row = mf * 16 + fq * 4 + r2;
            const int c   = nf * 16 + fr;
            if (c >= 16 && c < 46) GL[row * GSTR2 + (c - 16)] = ga[r2];
            if (wave == 0 && fr < 8 && fr == fq * 4 + r2) gdiag[fr] = ga[r2];
        }
    }
    __syncthreads();

    // ---- Epilogue: 1 pair per 16-lane quad, 32 quads, 3 rounds (88 pairs).
    // Stats from G; ln_g/ln_b/W2 streamed from global (L1-hot, c<300 guard).
    const int quad = lane >> 4, fl = lane & 15;
    const int qq = wave * 4 + quad;            // 0..31
    const float b2v = b2[0];
    const float inv = 1.f / (float)H_DIM;

    for (int round = 0; round < 3; ++round) {
        const int q = round * 32 + qq;          // 0..95
        const int qc = q < NPAIR - 1 ? q : NPAIR - 1;
        const int di = qc / NREL, rr = qc % NREL;
        const int ii = i0 + di, j = ii - KWIN + rr;
        const bool active = (q < NPAIR) && (j >= 0) && (j < L_SEQ);

        const int iA = di;                 // Ae row in X
        const int jA = 16 + di + rr;       // Ac row (16..33)
        const int pA = 34 + rr;            // Pb row (34..44)

        const float Se  = GL[iA * GSTR2 + 29];          // col 45 (ones)
        const float Sc  = GL[jA * GSTR2 + 29];
        const float Sp  = GL[pA * GSTR2 + 29];
        const float SSe = gdiag[iA];
        const float SSc = GL[jA * GSTR2 + (jA - 16)];
        const float SSp = GL[pA * GSTR2 + (pA - 16)];
        const float Dec = GL[iA * GSTR2 + (jA - 16)];
        const float Dep = GL[iA * GSTR2 + (pA - 16)];
        const float Dcp = GL[jA * GSTR2 + (pA - 16)];

        const float mu   = (Se + Sc + Sp) * inv;
        const float ss   = SSe + SSc + SSp + 2.f * (Dec + Dep + Dcp);
        const float rsig = rsqrtf(ss * inv - mu * mu + LN_EPS);
        const float nmrs = -mu * rsig;

        const int ea = iA * XSTR, ca = jA * XSTR, pa = pA * XSTR;

        float acc2 = 0.f;
#pragma unroll
        for (int w5 = 0; w5 < 5; ++w5) {
            const int c = w5 * 64 + fl * 4;     // 0..316
            if (w5 < 4 || c < 300) {            // tail guard (300 % 4 == 0)
                s16x4 a0 = *(const s16x4*)&X[ea + c];
                s16x4 d0 = *(const s16x4*)&X[ca + c];
                s16x4 p0 = *(const s16x4*)&X[pa + c];
                float4 g  = *(const float4*)(ln_g + c);
                float4 bb = *(const float4*)(ln_b + c);
                float4 w  = *(const float4*)(W2 + c);
#pragma unroll
                for (int e = 0; e < 4; ++e) {
                    float v = bf2f(a0[e]) + bf2f(d0[e]) + bf2f(p0[e]);
                    float t0 = fmaf(fmaf(v, rsig, nmrs), (&g.x)[e], (&bb.x)[e]);
                    t0 = t0 > 0.f ? t0 : __expf(t0) - 1.f;
                    acc2 = fmaf(t0, (&w.x)[e], acc2);
                }
            }
        }
#pragma unroll
        for (int off = 1; off < 16; off <<= 1) acc2 += __shfl_xor(acc2, off);

        if (fl == 0 && active) {
            const int jb = ii - KWIN < 0 ? 0 : ii - KWIN;
            const int n = rowstart(ii) + (j - jb);
            out[(size_t)b * NC + n] = acc2 + b2v;
            if (b == 0) {
                posout[2 * (size_t)n]     = (float)(ii + 1);
                posout[2 * (size_t)n + 1] = (float)(j + 1);
            }
        }
    }
}

// ---------------------------------------------------------------------------
extern "C" void kernel_launch(void* const* d_in, const int* in_sizes, int n_in,
                              void* d_out, int out_size, void* d_ws, size_t ws_size,
                              hipStream_t stream) {
    const float* h_e     = (const float*)d_in[0];
    const float* h_c     = (const float*)d_in[1];
    const float* h_share = (const float*)d_in[2];
    // d_in[3] = mask (unused)
    const float* pos_W   = (const float*)d_in[4];
    const float* W1      = (const float*)d_in[5];
    const float* b1      = (const float*)d_in[6];
    const float* ln_g    = (const float*)d_in[7];
    const float* ln_b    = (const float*)d_in[8];
    const float* W2      = (const float*)d_in[9];
    const float* b2      = (const float*)d_in[10];

    float* ws     = (float*)d_ws;
    short* prelbf = (short*)ws;
    short* Wb     = (short*)(ws + WB_OFF);

    float* out    = (float*)d_out;
    float* posout = out + BNC;

    prep_kernel<<<15 + (2 * WNPAD * WKSTR) / 256, 256, 0, stream>>>(
        pos_W, W1, b1, prelbf, Wb);

    fused_kernel<<<NB * (L_SEQ / ITILE), 512, 0, stream>>>(
        h_e, h_c, h_share, Wb, prelbf, ln_g, ln_b, W2, b2, out, posout);
}

// Round 2
// 183.915 us; speedup vs baseline: 1.1441x; 1.1441x over previous
//
#include <hip/hip_runtime.h>
#include <hip/hip_bf16.h>
#include <math.h>

// Problem constants
#define L_SEQ   1024
#define NB      8
#define H_DIM   300
#define KWIN    5
#define NREL    11          // 2K+1
#define PDIM    50
#define NC      11234       // band pair count for L=1024, K=5
#define BNC     (NB*NC)     // 89872
#define LN_EPS  1e-5f

#define KPAD    320         // K padded with zeros in [300,320)
#define WKSTR   320         // Wb k-stride (shorts)
#define WNPAD   320         // Wb padded n rows

#define ITILE   6           // i rows per block -> hc halo = 16 rows = 1 MFMA tile
#define NTILE   171         // ceil(1024/6)
#define HROWS   16          // hc halo rows: i0-5 .. i0+10
#define XROWS   48          // 0..5 he/Ae, 6..15 zero, 16..31 hc/Ac,
                            // 32..42 Pb, 43 ones, 44..47 zero
#define XSTR    328         // X row stride in shorts
#define GSTR2   28          // GL row stride (floats); stores G cols 16..43
#define ONESC   27          // compact col of the ones column (43-16)
#define NPAIR   (ITILE*NREL)  // 66

// Workspace layout (float offsets)
#define WB_OFF   2048       // prelbf (11*328 shorts = 7216 B) lives at 0
                            // Wb: 2*320*320 shorts = 102400 floats

typedef __attribute__((ext_vector_type(8))) short s16x8;
typedef __attribute__((ext_vector_type(4))) short s16x4;
typedef __attribute__((ext_vector_type(4))) float f32x4;

__device__ __forceinline__ short f2bf(float f) {
    unsigned u = __float_as_uint(f);
    u += 0x7fffu + ((u >> 16) & 1u);
    return (short)(u >> 16);
}
__device__ __forceinline__ float bf2f(short s) {
    return __uint_as_float(((unsigned)(unsigned short)s) << 16);
}

// band row start: first linear index n of row i
__device__ __forceinline__ int rowstart(int i) {
    if (i < 5)     return 6 * i + (i * (i - 1)) / 2;
    if (i <= 1018) return 40 + (i - 5) * 11;
    int d = i - 1019;
    return 11194 + d * 10 - (d * (d - 1)) / 2;
}

// ---------------------------------------------------------------------------
// Kernel 1: prep (unchanged).
//  blocks 0..14   : prelbf[r][h] = bf16(b1[h] + sum_d W1[h][600+d]*emb11[r][d]),
//                   stride 328, zero pad h>=300
//  blocks 15..814 : Wb[z][n][k] = bf16(W1[n][z*300+k]), zero-padded
__global__ __launch_bounds__(256) void prep_kernel(
    const float* __restrict__ pos_W, const float* __restrict__ W1,
    const float* __restrict__ b1, short* __restrict__ prelbf,
    short* __restrict__ Wb)
{
    if (blockIdx.x < 15) {
        __shared__ float semb[NREL * PDIM];
        for (int t = threadIdx.x; t < NREL * PDIM; t += 256) {
            int r = t / PDIM, d = t % PDIM;
            float acc = 0.f;
#pragma unroll
            for (int r2 = 0; r2 < NREL; ++r2) {
                float cnt = (float)(L_SEQ - abs(r2 - KWIN));
                int dr = r - r2;
                acc += cnt * expf(-(float)(dr * dr)) * pos_W[r2 * PDIM + d];
            }
            semb[t] = acc;
        }
        __syncthreads();
        int t = blockIdx.x * 256 + threadIdx.x;
        if (t < NREL * XSTR) {
            int r = t / XSTR, h = t % XSTR;
            float acc = 0.f;
            if (h < H_DIM) {
                acc = b1[h];
                const float* wrow = W1 + (size_t)h * 650 + 600;
                const float* em = semb + r * PDIM;
#pragma unroll 10
                for (int d = 0; d < PDIM; ++d) acc += wrow[d] * em[d];
            }
            prelbf[t] = (h < H_DIM) ? f2bf(acc) : (short)0;
        }
    } else {
        int id = (blockIdx.x - 15) * 256 + threadIdx.x;
        if (id < 2 * WNPAD * WKSTR) {
            int z = id / (WNPAD * WKSTR);
            int rem = id % (WNPAD * WKSTR);
            int n = rem / WKSTR, k = rem % WKSTR;
            float v = (n < H_DIM && k < H_DIM) ? W1[(size_t)n * 650 + z * H_DIM + k] : 0.f;
            Wb[id] = f2bf(v);
        }
    }
}

// ---------------------------------------------------------------------------
// Kernel 2: fused GEMM + Gram mini-GEMM + epilogue.
// Block = (b, i-tile of 6), 512 threads (8 waves), grid 1368.
// ITILE=6 makes the hc halo exactly 16 rows = 1 MFMA tile, so every wave has
// a single acc[5] (20 regs). launch_bounds(512,6) caps unified RF at ~85
// (demand ~72 -> no spill) -> 3 blocks/CU, 24 waves/CU. LDS ~36.9 KB.
__global__ __launch_bounds__(512, 6) void fused_kernel(
    const float* __restrict__ h_e, const float* __restrict__ h_c,
    const float* __restrict__ h_share, const short* __restrict__ Wb,
    const short* __restrict__ prelbf,
    const float* __restrict__ ln_g, const float* __restrict__ ln_b,
    const float* __restrict__ W2, const float* __restrict__ b2,
    float* __restrict__ out, float* __restrict__ posout)
{
    __shared__ __align__(16) short X[XROWS * XSTR];    // 31488 B
    __shared__ __align__(16) float GL[XROWS * GSTR2];  // 5376 B
    __shared__ __align__(16) float gdiag[8];           // SSe (diag rows 0..5)

    const int tid = threadIdx.x;
    const int b   = blockIdx.x / NTILE;
    const int i0  = (blockIdx.x % NTILE) * ITILE;

    // ---- zero-fill: rows 6..15 & 44..47 full width (14*41 chunks) + rows
    // 0..5,16..31 cols [304,328) (22*3 chunks) = 640 16B chunks
    for (int t = tid; t < 640; t += 512) {
        int row, c;
        if (t < 574) { int rr2 = t / 41; row = rr2 < 10 ? 6 + rr2 : 44 + (rr2 - 10); c = (t % 41) * 8; }
        else         { int u = t - 574; int r = u / 3; row = r < 6 ? r : 16 + (r - 6); c = 304 + (u % 3) * 8; }
        *(s16x8*)&X[row * XSTR + c] = (s16x8){0,0,0,0,0,0,0,0};
    }
    // ---- ones row (43): bf16(1.0)=0x3F80 for cols<300, else 0
    for (int t = tid; t < XSTR; t += 512)
        X[43 * XSTR + t] = (t < H_DIM) ? (short)0x3F80 : (short)0;
    // ---- Pb rows 32..42: straight copy from prelbf (layout matches)
    for (int t = tid; t < NREL * 41; t += 512) {
        int r = t / 41, c = (t % 41) * 8;
        *(s16x8*)&X[(32 + r) * XSTR + c] = *(const s16x8*)(prelbf + r * XSTR + c);
    }
    // ---- stage 16 halo rows; h_share read once per row.
    for (int t = tid; t < HROWS * 76; t += 512) {
        int s = t / 76, kc = (t % 76) * 4;
        int g = i0 - KWIN + s;
        bool valid = (kc < H_DIM) && (g >= 0) && (g < L_SEQ);
        float4 hs4 = make_float4(0.f,0.f,0.f,0.f), hc4 = hs4;
        size_t off = 0;
        if (valid) {
            off = ((size_t)b * L_SEQ + g) * H_DIM + kc;
            hs4 = *(const float4*)(h_share + off);
            hc4 = *(const float4*)(h_c + off);
        }
        s16x4 vc = { f2bf(hc4.x + hs4.x), f2bf(hc4.y + hs4.y),
                     f2bf(hc4.z + hs4.z), f2bf(hc4.w + hs4.w) };
        *(s16x4*)&X[(16 + s) * XSTR + kc] = vc;
        if (s >= KWIN && s < KWIN + ITILE) {   // he row: g = i0 + (s-5)
            float4 he4 = make_float4(0.f,0.f,0.f,0.f);
            if (valid) he4 = *(const float4*)(h_e + off);
            s16x4 ve = { f2bf(he4.x + hs4.x), f2bf(he4.y + hs4.y),
                         f2bf(he4.z + hs4.z), f2bf(he4.w + hs4.w) };
            *(s16x4*)&X[(s - KWIN) * XSTR + kc] = ve;
        }
    }
    __syncthreads();

    // ---- Main GEMM. 8 waves: wz = wave>>2 (0: Ae tile rows 0..15 with W1e,
    // 1: Ac tile rows 16..31 with W1c), nsl = (wave&3)*80. One acc[5] per wave.
    const int wave = tid >> 6, lane = tid & 63;
    const int fr = lane & 15, fq = lane >> 4;
    const int wz  = wave >> 2;
    const int nsl = (wave & 3) * 80;
    const short* wbase = Wb + ((size_t)(wz * WNPAD + nsl + fr)) * WKSTR + fq * 8;

    const int arow = (wz ? 16 : 0) + fr;

    f32x4 acc0[5] = {};

    for (int k0 = 0; k0 < KPAD; k0 += 32) {
        s16x8 bf[5];
#pragma unroll
        for (int nt = 0; nt < 5; ++nt)
            bf[nt] = *(const s16x8*)(wbase + (size_t)nt * 16 * WKSTR + k0);
        s16x8 af0 = *(const s16x8*)&X[arow * XSTR + k0 + fq * 8];
#pragma unroll
        for (int nt = 0; nt < 5; ++nt)
            acc0[nt] = __builtin_amdgcn_mfma_f32_16x16x32_bf16(af0, bf[nt], acc0[nt], 0, 0, 0);
    }
    __syncthreads();   // all waves done reading X inputs

    // ---- write Ae/Ac into X (bf16). C/D: col = nsl+nt*16+fr, row = fq*4+r2.
    // Zero A-rows compute to zero -> rows 6..15 stay zero.
    {
        const int rbase = (wz ? 16 : 0) + fq * 4;
#pragma unroll
        for (int nt = 0; nt < 5; ++nt) {
            const int col = nsl + nt * 16 + fr;     // cols>=300 compute to 0
#pragma unroll
            for (int r2 = 0; r2 < 4; ++r2)
                X[(rbase + r2) * XSTR + col] = f2bf(acc0[nt][r2]);
        }
    }
    __syncthreads();

    // ---- Gram mini-GEMM: needed frags of the 3x3 grid over 48 rows (k=320).
    // Waves 0..5 -> frags (0,0)d,(0,1),(0,2),(1,1),(1,2),(2,2).
    // Only cols 16..43 are read -> compact store (col-16); diag of frag (0,0)
    // stashed in gdiag for SSe.
    if (wave < 6) {
        const int mf = (wave < 3) ? 0 : (wave < 5 ? 1 : 2);
        const int nf = (wave < 3) ? wave : (wave < 5 ? wave - 2 : 2);
        f32x4 ga = {};
        for (int k0 = 0; k0 < KPAD; k0 += 32) {
            s16x8 av = *(const s16x8*)&X[(mf * 16 + fr) * XSTR + k0 + fq * 8];
            s16x8 bv = *(const s16x8*)&X[(nf * 16 + fr) * XSTR + k0 + fq * 8];
            ga = __builtin_amdgcn_mfma_f32_16x16x32_bf16(av, bv, ga, 0, 0, 0);
        }
#pragma unroll
        for (int r2 = 0; r2 < 4; ++r2) {
            const int row = mf * 16 + fq * 4 + r2;
            const int c   = nf * 16 + fr;
            if (c >= 16 && c < 44) GL[row * GSTR2 + (c - 16)] = ga[r2];
            if (wave == 0 && fr < ITILE && fr == fq * 4 + r2) gdiag[fr] = ga[r2];
        }
    }
    __syncthreads();

    // ---- Epilogue: 1 pair per 16-lane quad, 32 quads, 3 rounds (66 pairs).
    // Stats from G; ln_g/ln_b/W2 streamed from global (L1-hot, c<300 guard).
    const int quad = lane >> 4, fl = lane & 15;
    const int qq = wave * 4 + quad;            // 0..31
    const float b2v = b2[0];
    const float inv = 1.f / (float)H_DIM;

    for (int round = 0; round < 3; ++round) {
        const int q = round * 32 + qq;          // 0..95
        const int qc = q < NPAIR - 1 ? q : NPAIR - 1;
        const int di = qc / NREL, rr = qc % NREL;
        const int ii = i0 + di, j = ii - KWIN + rr;
        const bool active = (q < NPAIR) && (ii < L_SEQ) && (j >= 0) && (j < L_SEQ);

        const int iA = di;                 // Ae row in X (0..5)
        const int jA = 16 + di + rr;       // Ac row (16..31)
        const int pA = 32 + rr;            // Pb row (32..42)

        const float Se  = GL[iA * GSTR2 + ONESC];
        const float Sc  = GL[jA * GSTR2 + ONESC];
        const float Sp  = GL[pA * GSTR2 + ONESC];
        const float SSe = gdiag[iA];
        const float SSc = GL[jA * GSTR2 + (jA - 16)];
        const float SSp = GL[pA * GSTR2 + (pA - 16)];
        const float Dec = GL[iA * GSTR2 + (jA - 16)];
        const float Dep = GL[iA * GSTR2 + (pA - 16)];
        const float Dcp = GL[jA * GSTR2 + (pA - 16)];

        const float mu   = (Se + Sc + Sp) * inv;
        const float ss   = SSe + SSc + SSp + 2.f * (Dec + Dep + Dcp);
        const float rsig = rsqrtf(ss * inv - mu * mu + LN_EPS);
        const float nmrs = -mu * rsig;

        const int ea = iA * XSTR, ca = jA * XSTR, pa = pA * XSTR;

        float acc2 = 0.f;
#pragma unroll
        for (int w5 = 0; w5 < 5; ++w5) {
            const int c = w5 * 64 + fl * 4;     // 0..316
            if (w5 < 4 || c < 300) {            // tail guard (300 % 4 == 0)
                s16x4 a0 = *(const s16x4*)&X[ea + c];
                s16x4 d0 = *(const s16x4*)&X[ca + c];
                s16x4 p0 = *(const s16x4*)&X[pa + c];
                float4 g  = *(const float4*)(ln_g + c);
                float4 bb = *(const float4*)(ln_b + c);
                float4 w  = *(const float4*)(W2 + c);
#pragma unroll
                for (int e = 0; e < 4; ++e) {
                    float v = bf2f(a0[e]) + bf2f(d0[e]) + bf2f(p0[e]);
                    float t0 = fmaf(fmaf(v, rsig, nmrs), (&g.x)[e], (&bb.x)[e]);
                    t0 = t0 > 0.f ? t0 : __expf(t0) - 1.f;
                    acc2 = fmaf(t0, (&w.x)[e], acc2);
                }
            }
        }
#pragma unroll
        for (int off = 1; off < 16; off <<= 1) acc2 += __shfl_xor(acc2, off);

        if (fl == 0 && active) {
            const int jb = ii - KWIN < 0 ? 0 : ii - KWIN;
            const int n = rowstart(ii) + (j - jb);
            out[(size_t)b * NC + n] = acc2 + b2v;
            if (b == 0) {
                posout[2 * (size_t)n]     = (float)(ii + 1);
                posout[2 * (size_t)n + 1] = (float)(j + 1);
            }
        }
    }
}

// ---------------------------------------------------------------------------
extern "C" void kernel_launch(void* const* d_in, const int* in_sizes, int n_in,
                              void* d_out, int out_size, void* d_ws, size_t ws_size,
                              hipStream_t stream) {
    const float* h_e     = (const float*)d_in[0];
    const float* h_c     = (const float*)d_in[1];
    const float* h_share = (const float*)d_in[2];
    // d_in[3] = mask (unused)
    const float* pos_W   = (const float*)d_in[4];
    const float* W1      = (const float*)d_in[5];
    const float* b1      = (const float*)d_in[6];
    const float* ln_g    = (const float*)d_in[7];
    const float* ln_b    = (const float*)d_in[8];
    const float* W2      = (const float*)d_in[9];
    const float* b2      = (const float*)d_in[10];

    float* ws     = (float*)d_ws;
    short* prelbf = (short*)ws;
    short* Wb     = (short*)(ws + WB_OFF);

    float* out    = (float*)d_out;
    float* posout = out + BNC;

    prep_kernel<<<15 + (2 * WNPAD * WKSTR) / 256, 256, 0, stream>>>(
        pos_W, W1, b1, prelbf, Wb);

    fused_kernel<<<NB * NTILE, 512, 0, stream>>>(
        h_e, h_c, h_share, Wb, prelbf, ln_g, ln_b, W2, b2, out, posout);
}

// Round 3
// 170.979 us; speedup vs baseline: 1.2307x; 1.0757x over previous
//
#include <hip/hip_runtime.h>
#include <hip/hip_bf16.h>
#include <math.h>

// Problem constants
#define L_SEQ   1024
#define NB      8
#define H_DIM   300
#define KWIN    5
#define NREL    11          // 2K+1
#define PDIM    50
#define NC      11234       // band pair count for L=1024, K=5
#define BNC     (NB*NC)     // 89872
#define LN_EPS  1e-5f

#define KPAD    320         // K padded with zeros in [300,320)
#define WKSTR   320         // Wb k-stride (shorts)
#define WNPAD   320         // Wb padded n rows

#define ITILE   6           // i rows per block (per batch)
#define NTILE   171         // ceil(1024/6)
#define THREADS 768         // 12 waves
#define XROWS   64          // 0..11 he b0/b1 (+12..15 z), 16..31 hc b0,
                            // 32..47 hc b1, 48..58 Pb, 59 ones, 60..63 z
#define XSTR    328         // X row stride in shorts
#define GLF     272         // per-frag floats (16 rows x stride 17)
#define NPAIR2  132         // 2 batches x 66 pairs

// Workspace layout (float offsets)
#define WB_OFF   2048       // prelbf (11*328 shorts = 7216 B) lives at 0
                            // Wb: 2*320*320 shorts = 102400 floats

typedef __attribute__((ext_vector_type(8))) short s16x8;
typedef __attribute__((ext_vector_type(4))) short s16x4;
typedef __attribute__((ext_vector_type(4))) float f32x4;

__device__ __forceinline__ short f2bf(float f) {
    unsigned u = __float_as_uint(f);
    u += 0x7fffu + ((u >> 16) & 1u);
    return (short)(u >> 16);
}
__device__ __forceinline__ float bf2f(short s) {
    return __uint_as_float(((unsigned)(unsigned short)s) << 16);
}

// band row start: first linear index n of row i
__device__ __forceinline__ int rowstart(int i) {
    if (i < 5)     return 6 * i + (i * (i - 1)) / 2;
    if (i <= 1018) return 40 + (i - 5) * 11;
    int d = i - 1019;
    return 11194 + d * 10 - (d * (d - 1)) / 2;
}

// ---------------------------------------------------------------------------
// Kernel 1: prep.
//  blocks 0..14  : prelbf[r][h] = bf16(b1[h] + sum_d W1[h][600+d]*emb11[r][d])
//  blocks 15..114: Wb[z][n][k] = bf16(W1[n][z*300+k]) vectorized s16x8 stores
__global__ __launch_bounds__(256) void prep_kernel(
    const float* __restrict__ pos_W, const float* __restrict__ W1,
    const float* __restrict__ b1, short* __restrict__ prelbf,
    short* __restrict__ Wb)
{
    if (blockIdx.x < 15) {
        __shared__ float semb[NREL * PDIM];
        for (int t = threadIdx.x; t < NREL * PDIM; t += 256) {
            int r = t / PDIM, d = t % PDIM;
            float acc = 0.f;
#pragma unroll
            for (int r2 = 0; r2 < NREL; ++r2) {
                float cnt = (float)(L_SEQ - abs(r2 - KWIN));
                int dr = r - r2;
                acc += cnt * expf(-(float)(dr * dr)) * pos_W[r2 * PDIM + d];
            }
            semb[t] = acc;
        }
        __syncthreads();
        int t = blockIdx.x * 256 + threadIdx.x;
        if (t < NREL * XSTR) {
            int r = t / XSTR, h = t % XSTR;
            float acc = 0.f;
            if (h < H_DIM) {
                acc = b1[h];
                const float* wrow = W1 + (size_t)h * 650 + 600;
                const float* em = semb + r * PDIM;
#pragma unroll 10
                for (int d = 0; d < PDIM; ++d) acc += wrow[d] * em[d];
            }
            prelbf[t] = (h < H_DIM) ? f2bf(acc) : (short)0;
        }
    } else {
        // 2*320*320 shorts = 25600 s16x8 chunks over 100 blocks
        int c = (blockIdx.x - 15) * 256 + threadIdx.x;
        if (c < 25600) {
            int z   = c / 12800;
            int rem = c - z * 12800;
            int n   = rem / 40;
            int k0  = (rem - n * 40) * 8;
            s16x8 v8 = (s16x8){0,0,0,0,0,0,0,0};
            if (n < H_DIM) {
                const float* base = W1 + (size_t)n * 650 + z * H_DIM;
#pragma unroll
                for (int e = 0; e < 8; ++e) {
                    int k = k0 + e;
                    float v = 0.f;
                    if (k < H_DIM) v = base[k];
                    v8[e] = f2bf(v);
                }
            }
            *(s16x8*)&Wb[(size_t)c * 8] = v8;
        }
    }
}

// ---------------------------------------------------------------------------
// Kernel 2: fused GEMM + Gram + epilogue. Block = (batch-pair, i-tile of 6),
// 768 threads (12 waves), grid 684. 3 full M-tiles (he b0+b1 / hc b0 / hc b1)
// x 4 N-slices = 12 jobs = 1 per wave, acc[5]=20 regs, no clamps.
// LDS ~55.6 KB; launch_bounds(768,6) -> 2 blocks/CU = 24 waves (75%),
// reg cap 85 vs demand ~76 -> no spill.
__global__ __launch_bounds__(THREADS, 6) void fused_kernel(
    const float* __restrict__ h_e, const float* __restrict__ h_c,
    const float* __restrict__ h_share, const short* __restrict__ Wb,
    const short* __restrict__ prelbf,
    const float* __restrict__ ln_g, const float* __restrict__ ln_b,
    const float* __restrict__ W2, const float* __restrict__ b2,
    float* __restrict__ out, float* __restrict__ posout)
{
    __shared__ __align__(16) short X[XROWS * XSTR];   // 41984 B
    __shared__ __align__(16) float GL[9 * GLF];       // 9792 B
    __shared__ __align__(16) float SG[320];
    __shared__ __align__(16) float SB[320];
    __shared__ __align__(16) float SW[320];

    const int tid = threadIdx.x;
    const int bp  = blockIdx.x / NTILE;       // batch pair 0..3
    const int i0  = (blockIdx.x % NTILE) * ITILE;

    // ---- zero-fill: rows 12..15 & 60..63 full width (8*41) + rows 0..11,
    // 16..47 cols [304,328) (44*3) = 460 16B chunks
    for (int t = tid; t < 460; t += THREADS) {
        int row, c;
        if (t < 328) { int rr2 = t / 41; row = rr2 < 4 ? 12 + rr2 : 60 + (rr2 - 4); c = (t % 41) * 8; }
        else         { int u = t - 328; int r = u / 3; row = r < 12 ? r : 16 + (r - 12); c = 304 + (u % 3) * 8; }
        *(s16x8*)&X[row * XSTR + c] = (s16x8){0,0,0,0,0,0,0,0};
    }
    // ---- ones row (59): bf16(1.0)=0x3F80 for cols<300, else 0
    for (int t = tid; t < XSTR; t += THREADS)
        X[59 * XSTR + t] = (t < H_DIM) ? (short)0x3F80 : (short)0;
    // ---- Pb rows 48..58: straight copy from prelbf (layout matches)
    for (int t = tid; t < NREL * 41; t += THREADS) {
        int r = t / 41, c = (t % 41) * 8;
        *(s16x8*)&X[(48 + r) * XSTR + c] = *(const s16x8*)(prelbf + r * XSTR + c);
    }
    // ---- LN params to LDS (zero pad to 320)
    if (tid < 320) {
        bool v = tid < H_DIM;
        SG[tid] = v ? ln_g[tid] : 0.f;
        SB[tid] = v ? ln_b[tid] : 0.f;
        SW[tid] = v ? W2[tid]   : 0.f;
    }
    // ---- stage 2 batches x 16 halo rows; h_share read once per row.
    for (int t = tid; t < 32 * 76; t += THREADS) {
        int s = t / 76, kc = (t % 76) * 4;
        int bb = s >> 4, sr = s & 15;
        int g = i0 - KWIN + sr;
        int b = bp * 2 + bb;
        bool valid = (kc < H_DIM) && (g >= 0) && (g < L_SEQ);
        float4 hs4 = make_float4(0.f,0.f,0.f,0.f), hc4 = hs4;
        size_t off = 0;
        if (valid) {
            off = ((size_t)b * L_SEQ + g) * H_DIM + kc;
            hs4 = *(const float4*)(h_share + off);
            hc4 = *(const float4*)(h_c + off);
        }
        s16x4 vc = { f2bf(hc4.x + hs4.x), f2bf(hc4.y + hs4.y),
                     f2bf(hc4.z + hs4.z), f2bf(hc4.w + hs4.w) };
        *(s16x4*)&X[(16 + bb * 16 + sr) * XSTR + kc] = vc;
        if (sr >= KWIN && sr < KWIN + ITILE) {   // he row: g = i0 + (sr-5)
            float4 he4 = make_float4(0.f,0.f,0.f,0.f);
            if (valid) he4 = *(const float4*)(h_e + off);
            s16x4 ve = { f2bf(he4.x + hs4.x), f2bf(he4.y + hs4.y),
                         f2bf(he4.z + hs4.z), f2bf(he4.w + hs4.w) };
            *(s16x4*)&X[(bb * 6 + sr - KWIN) * XSTR + kc] = ve;
        }
    }
    __syncthreads();

    // ---- Main GEMM. 12 waves: mt = wave>>2 (tile 0: he both batches with
    // W1e; tiles 1,2: hc b0/b1 with W1c), nsl = (wave&3)*80. One acc[5]/wave.
    const int wave = tid >> 6, lane = tid & 63;
    const int fr = lane & 15, fq = lane >> 4;
    const int mt  = wave >> 2;
    const int nsl = (wave & 3) * 80;
    const int whalf = mt ? 1 : 0;
    const short* wbase = Wb + ((size_t)(whalf * WNPAD + nsl + fr)) * WKSTR + fq * 8;
    const int arow = mt * 16 + fr;

    f32x4 acc0[5] = {};

    for (int k0 = 0; k0 < KPAD; k0 += 32) {
        s16x8 bf[5];
#pragma unroll
        for (int nt = 0; nt < 5; ++nt)
            bf[nt] = *(const s16x8*)(wbase + (size_t)nt * 16 * WKSTR + k0);
        s16x8 af0 = *(const s16x8*)&X[arow * XSTR + k0 + fq * 8];
#pragma unroll
        for (int nt = 0; nt < 5; ++nt)
            acc0[nt] = __builtin_amdgcn_mfma_f32_16x16x32_bf16(af0, bf[nt], acc0[nt], 0, 0, 0);
    }
    __syncthreads();   // all waves done reading X inputs

    // ---- write Ae/Ac into X (bf16). C/D: col = nsl+nt*16+fr, row = fq*4+r2.
    // All 48 A-rows are full tiles; zero rows compute to zero.
    {
        const int rbase = mt * 16 + fq * 4;
#pragma unroll
        for (int nt = 0; nt < 5; ++nt) {
            const int col = nsl + nt * 16 + fr;     // cols>=300 compute to 0
#pragma unroll
            for (int r2 = 0; r2 < 4; ++r2)
                X[(rbase + r2) * XSTR + col] = f2bf(acc0[nt][r2]);
        }
    }
    __syncthreads();

    // ---- Gram: 9 needed frags of the 4x4 tile grid over 64 rows (k=320).
    // waves 0..8 -> (0,0),(0,1),(0,2),(0,3),(1,1),(2,2),(1,3),(2,3),(3,3).
    // Stored fragment-indexed, stride 17 (bank-friendly).
    if (wave < 9) {
        const int mf = (wave < 4) ? 0 : ((wave == 4 || wave == 6) ? 1 : ((wave == 8) ? 3 : 2));
        const int nf = (wave < 4) ? wave : ((wave < 6) ? (wave - 3) : 3);
        f32x4 ga = {};
        for (int k0 = 0; k0 < KPAD; k0 += 32) {
            s16x8 av = *(const s16x8*)&X[(mf * 16 + fr) * XSTR + k0 + fq * 8];
            s16x8 bv = *(const s16x8*)&X[(nf * 16 + fr) * XSTR + k0 + fq * 8];
            ga = __builtin_amdgcn_mfma_f32_16x16x32_bf16(av, bv, ga, 0, 0, 0);
        }
#pragma unroll
        for (int r2 = 0; r2 < 4; ++r2)
            GL[wave * GLF + (fq * 4 + r2) * 17 + fr] = ga[r2];
    }
    __syncthreads();

    // ---- Epilogue: 1 pair per 16-lane quad, 48 quads, 3 rounds (132 pairs).
    // Frag indices: tile3 col 0..10 = Pb rr, col 11 = ones row.
    const int quad = lane >> 4, fl = lane & 15;
    const int qq = wave * 4 + quad;            // 0..47
    const float b2v = b2[0];
    const float inv = 1.f / (float)H_DIM;

    for (int round = 0; round < 3; ++round) {
        const int q = round * 48 + qq;          // 0..143
        const int qc = q < NPAIR2 - 1 ? q : NPAIR2 - 1;
        const int bb = qc >= 66 ? 1 : 0;
        const int qr = qc - bb * 66;
        const int di = qr / NREL, rr = qr % NREL;
        const int ii = i0 + di, j = ii - KWIN + rr;
        const bool active = (q < NPAIR2) && (ii < L_SEQ) && (j >= 0) && (j < L_SEQ);

        const int he_l = bb * 6 + di;       // row in tile0 (0..11)
        const int hr   = di + rr;           // row within hc tile (0..15)
        const int pr   = rr;                // row within tile3 (0..10)

        const float Se  = GL[3 * GLF + he_l * 17 + 11];
        const float SSe = GL[0 * GLF + he_l * 17 + he_l];
        const float Sc  = GL[(6 + bb) * GLF + hr * 17 + 11];
        const float SSc = GL[(4 + bb) * GLF + hr * 17 + hr];
        const float Sp  = GL[8 * GLF + pr * 17 + 11];
        const float SSp = GL[8 * GLF + pr * 17 + pr];
        const float Dec = GL[(1 + bb) * GLF + he_l * 17 + hr];
        const float Dep = GL[3 * GLF + he_l * 17 + pr];
        const float Dcp = GL[(6 + bb) * GLF + hr * 17 + pr];

        const float mu   = (Se + Sc + Sp) * inv;
        const float ss   = SSe + SSc + SSp + 2.f * (Dec + Dep + Dcp);
        const float rsig = rsqrtf(ss * inv - mu * mu + LN_EPS);
        const float nmrs = -mu * rsig;

        const int ea = he_l * XSTR;
        const int ca = (16 + bb * 16 + hr) * XSTR;
        const int pa = (48 + pr) * XSTR;

        float acc2 = 0.f;
#pragma unroll
        for (int w5 = 0; w5 < 5; ++w5) {
            const int c = w5 * 64 + fl * 4;     // 0..316, zero-padded
            s16x4 a0 = *(const s16x4*)&X[ea + c];
            s16x4 d0 = *(const s16x4*)&X[ca + c];
            s16x4 p0 = *(const s16x4*)&X[pa + c];
            float4 g  = *(const float4*)&SG[c];
            float4 bbv = *(const float4*)&SB[c];
            float4 w  = *(const float4*)&SW[c];
#pragma unroll
            for (int e = 0; e < 4; ++e) {
                float v = bf2f(a0[e]) + bf2f(d0[e]) + bf2f(p0[e]);
                float t0 = fmaf(fmaf(v, rsig, nmrs), (&g.x)[e], (&bbv.x)[e]);
                t0 = t0 > 0.f ? t0 : __expf(t0) - 1.f;
                acc2 = fmaf(t0, (&w.x)[e], acc2);
            }
        }
#pragma unroll
        for (int off = 1; off < 16; off <<= 1) acc2 += __shfl_xor(acc2, off);

        if (fl == 0 && active) {
            const int jb = ii - KWIN < 0 ? 0 : ii - KWIN;
            const int n = rowstart(ii) + (j - jb);
            const int b_out = bp * 2 + bb;
            out[(size_t)b_out * NC + n] = acc2 + b2v;
            if (b_out == 0) {
                posout[2 * (size_t)n]     = (float)(ii + 1);
                posout[2 * (size_t)n + 1] = (float)(j + 1);
            }
        }
    }
}

// ---------------------------------------------------------------------------
extern "C" void kernel_launch(void* const* d_in, const int* in_sizes, int n_in,
                              void* d_out, int out_size, void* d_ws, size_t ws_size,
                              hipStream_t stream) {
    const float* h_e     = (const float*)d_in[0];
    const float* h_c     = (const float*)d_in[1];
    const float* h_share = (const float*)d_in[2];
    // d_in[3] = mask (unused)
    const float* pos_W   = (const float*)d_in[4];
    const float* W1      = (const float*)d_in[5];
    const float* b1      = (const float*)d_in[6];
    const float* ln_g    = (const float*)d_in[7];
    const float* ln_b    = (const float*)d_in[8];
    const float* W2      = (const float*)d_in[9];
    const float* b2      = (const float*)d_in[10];

    float* ws     = (float*)d_ws;
    short* prelbf = (short*)ws;
    short* Wb     = (short*)(ws + WB_OFF);

    float* out    = (float*)d_out;
    float* posout = out + BNC;

    prep_kernel<<<115, 256, 0, stream>>>(pos_W, W1, b1, prelbf, Wb);

    fused_kernel<<<(NB / 2) * NTILE, THREADS, 0, stream>>>(
        h_e, h_c, h_share, Wb, prelbf, ln_g, ln_b, W2, b2, out, posout);
}

// Round 4
// 146.606 us; speedup vs baseline: 1.4353x; 1.1663x over previous
//
#include <hip/hip_runtime.h>
#include <hip/hip_bf16.h>
#include <math.h>

// Problem constants
#define L_SEQ   1024
#define NB      8
#define H_DIM   300
#define KWIN    5
#define NREL    11          // 2K+1
#define PDIM    50
#define NC      11234       // band pair count for L=1024, K=5
#define BNC     (NB*NC)     // 89872
#define LN_EPS  1e-5f

#define KPAD    320         // K padded with zeros in [300,320)
#define WKSTR   320         // Wb k-stride (shorts)
#define WNPAD   320         // Wb padded n rows

#define ITILE   16          // i rows per block
#define THREADS 768         // 12 waves
#define HROWS   26          // hc halo rows: i0-5 .. i0+20
#define XROWS   64          // 0..15 Ae/he, 16..41 Ac/hc, 42..47 zero,
                            // 48..58 Pb, 59 ones, 60..63 zero
#define XSTR    328         // X row stride in shorts
#define GSTR3   44          // GL row stride (floats); stores G cols 16..59
#define NPAIR   (ITILE*NREL)  // 176

// Workspace layout (float offsets)
#define WB_OFF   2048       // prelbf (11*328 shorts = 7216 B) lives at 0
                            // Wb: 2*320*320 shorts = 102400 floats

typedef __attribute__((ext_vector_type(8))) short s16x8;
typedef __attribute__((ext_vector_type(4))) short s16x4;
typedef __attribute__((ext_vector_type(4))) float f32x4;

__device__ __forceinline__ short f2bf(float f) {
    unsigned u = __float_as_uint(f);
    u += 0x7fffu + ((u >> 16) & 1u);
    return (short)(u >> 16);
}
__device__ __forceinline__ float bf2f(short s) {
    return __uint_as_float(((unsigned)(unsigned short)s) << 16);
}

// band row start: first linear index n of row i
__device__ __forceinline__ int rowstart(int i) {
    if (i < 5)     return 6 * i + (i * (i - 1)) / 2;
    if (i <= 1018) return 40 + (i - 5) * 11;
    int d = i - 1019;
    return 11194 + d * 10 - (d * (d - 1)) / 2;
}

// ---------------------------------------------------------------------------
// Kernel 1: prep.
//  blocks 0..14  : prelbf[r][h] = bf16(b1[h] + sum_d W1[h][600+d]*emb11[r][d])
//  blocks 15..114: Wb[z][n][k] = bf16(W1[n][z*300+k]) vectorized s16x8 stores
__global__ __launch_bounds__(256) void prep_kernel(
    const float* __restrict__ pos_W, const float* __restrict__ W1,
    const float* __restrict__ b1, short* __restrict__ prelbf,
    short* __restrict__ Wb)
{
    if (blockIdx.x < 15) {
        __shared__ float semb[NREL * PDIM];
        for (int t = threadIdx.x; t < NREL * PDIM; t += 256) {
            int r = t / PDIM, d = t % PDIM;
            float acc = 0.f;
#pragma unroll
            for (int r2 = 0; r2 < NREL; ++r2) {
                float cnt = (float)(L_SEQ - abs(r2 - KWIN));
                int dr = r - r2;
                acc += cnt * expf(-(float)(dr * dr)) * pos_W[r2 * PDIM + d];
            }
            semb[t] = acc;
        }
        __syncthreads();
        int t = blockIdx.x * 256 + threadIdx.x;
        if (t < NREL * XSTR) {
            int r = t / XSTR, h = t % XSTR;
            float acc = 0.f;
            if (h < H_DIM) {
                acc = b1[h];
                const float* wrow = W1 + (size_t)h * 650 + 600;
                const float* em = semb + r * PDIM;
#pragma unroll 10
                for (int d = 0; d < PDIM; ++d) acc += wrow[d] * em[d];
            }
            prelbf[t] = (h < H_DIM) ? f2bf(acc) : (short)0;
        }
    } else {
        // 2*320*320 shorts = 25600 s16x8 chunks over 100 blocks
        int c = (blockIdx.x - 15) * 256 + threadIdx.x;
        if (c < 25600) {
            int z   = c / 12800;
            int rem = c - z * 12800;
            int n   = rem / 40;
            int k0  = (rem - n * 40) * 8;
            s16x8 v8 = (s16x8){0,0,0,0,0,0,0,0};
            if (n < H_DIM) {
                const float* base = W1 + (size_t)n * 650 + z * H_DIM;
#pragma unroll
                for (int e = 0; e < 8; ++e) {
                    int k = k0 + e;
                    float v = 0.f;
                    if (k < H_DIM) v = base[k];
                    v8[e] = f2bf(v);
                }
            }
            *(s16x8*)&Wb[(size_t)c * 8] = v8;
        }
    }
}

// ---------------------------------------------------------------------------
// Kernel 2: fused GEMM + Gram mini-GEMM + epilogue.
// Block = (b, i-tile of 16), 768 threads (12 waves), grid 512.
// Main GEMM: 3 M-tiles x 4 N-slices = 12 jobs = 1/wave, single acc[5].
// NO min-waves launch_bounds arg (caps caused scratch spills in r1-r3).
// LDS ~57.2 KB -> 2 blocks/CU = 24 waves/CU if unified regs <= 85.
__global__ __launch_bounds__(THREADS) void fused_kernel(
    const float* __restrict__ h_e, const float* __restrict__ h_c,
    const float* __restrict__ h_share, const short* __restrict__ Wb,
    const short* __restrict__ prelbf,
    const float* __restrict__ ln_g, const float* __restrict__ ln_b,
    const float* __restrict__ W2, const float* __restrict__ b2,
    float* __restrict__ out, float* __restrict__ posout)
{
    __shared__ __align__(16) short X[XROWS * XSTR];    // 41984 B
    __shared__ __align__(16) float GL[XROWS * GSTR3];  // 11264 B
    __shared__ __align__(16) float SG[320];
    __shared__ __align__(16) float SB[320];
    __shared__ __align__(16) float SW[320];
    __shared__ __align__(16) float gdiag[16];          // SSe (diag rows 0..15)

    const int tid = threadIdx.x;
    const int b   = blockIdx.x >> 6;          // 64 i-tiles per batch
    const int i0  = (blockIdx.x & 63) * ITILE;

    // ---- zero-fill: rows 42..47 & 60..63 full width (10*41) + rows 0..41
    // cols [304,328) (42*3) = 536 16B chunks
    for (int t = tid; t < 536; t += THREADS) {
        int row, c;
        if (t < 410) { int rr2 = t / 41; row = rr2 < 6 ? 42 + rr2 : 60 + (rr2 - 6); c = (t % 41) * 8; }
        else         { int u = t - 410; row = u / 3; c = 304 + (u % 3) * 8; }
        *(s16x8*)&X[row * XSTR + c] = (s16x8){0,0,0,0,0,0,0,0};
    }
    // ---- ones row (59): bf16(1.0)=0x3F80 for cols<300, else 0
    for (int t = tid; t < XSTR; t += THREADS)
        X[59 * XSTR + t] = (t < H_DIM) ? (short)0x3F80 : (short)0;
    // ---- Pb rows 48..58: straight copy from prelbf (layout matches)
    for (int t = tid; t < NREL * 41; t += THREADS) {
        int r = t / 41, c = (t % 41) * 8;
        *(s16x8*)&X[(48 + r) * XSTR + c] = *(const s16x8*)(prelbf + r * XSTR + c);
    }
    // ---- LN params to LDS (zero pad to 320)
    if (tid < 320) {
        bool v = tid < H_DIM;
        SG[tid] = v ? ln_g[tid] : 0.f;
        SB[tid] = v ? ln_b[tid] : 0.f;
        SW[tid] = v ? W2[tid]   : 0.f;
    }
    // ---- stage 26 halo rows; h_share read once per row.
    for (int t = tid; t < HROWS * 76; t += THREADS) {
        int s = t / 76, kc = (t % 76) * 4;
        int g = i0 - KWIN + s;
        bool valid = (kc < H_DIM) && (g >= 0) && (g < L_SEQ);
        float4 hs4 = make_float4(0.f,0.f,0.f,0.f), hc4 = hs4;
        size_t off = 0;
        if (valid) {
            off = ((size_t)b * L_SEQ + g) * H_DIM + kc;
            hs4 = *(const float4*)(h_share + off);
            hc4 = *(const float4*)(h_c + off);
        }
        s16x4 vc = { f2bf(hc4.x + hs4.x), f2bf(hc4.y + hs4.y),
                     f2bf(hc4.z + hs4.z), f2bf(hc4.w + hs4.w) };
        *(s16x4*)&X[(16 + s) * XSTR + kc] = vc;
        if (s >= KWIN && s < KWIN + ITILE) {   // he row: g = i0 + (s-5)
            float4 he4 = make_float4(0.f,0.f,0.f,0.f);
            if (valid) he4 = *(const float4*)(h_e + off);
            s16x4 ve = { f2bf(he4.x + hs4.x), f2bf(he4.y + hs4.y),
                         f2bf(he4.z + hs4.z), f2bf(he4.w + hs4.w) };
            *(s16x4*)&X[(s - KWIN) * XSTR + kc] = ve;
        }
    }
    __syncthreads();

    // ---- Main GEMM. 12 waves: mt = wave>>2 (tile0 rows 0..15 = Ae w/ W1e;
    // tiles 1,2 rows 16..47 = Ac w/ W1c, rows 42..47 zero), nsl=(wave&3)*80.
    const int wave = tid >> 6, lane = tid & 63;
    const int fr = lane & 15, fq = lane >> 4;
    const int mt  = wave >> 2;
    const int nsl = (wave & 3) * 80;
    const int whalf = mt ? 1 : 0;
    const short* wbase = Wb + ((size_t)(whalf * WNPAD + nsl + fr)) * WKSTR + fq * 8;
    const int arow = mt * 16 + fr;

    f32x4 acc0[5] = {};

    for (int k0 = 0; k0 < KPAD; k0 += 32) {
        s16x8 bf[5];
#pragma unroll
        for (int nt = 0; nt < 5; ++nt)
            bf[nt] = *(const s16x8*)(wbase + (size_t)nt * 16 * WKSTR + k0);
        s16x8 af0 = *(const s16x8*)&X[arow * XSTR + k0 + fq * 8];
#pragma unroll
        for (int nt = 0; nt < 5; ++nt)
            acc0[nt] = __builtin_amdgcn_mfma_f32_16x16x32_bf16(af0, bf[nt], acc0[nt], 0, 0, 0);
    }
    __syncthreads();   // all waves done reading X inputs

    // ---- write Ae/Ac into X (bf16). C/D: col = nsl+nt*16+fr, row = fq*4+r2.
    // Zero A-rows (42..47) compute to zero -> stay zero. No clamps.
    {
        const int rbase = mt * 16 + fq * 4;
#pragma unroll
        for (int nt = 0; nt < 5; ++nt) {
            const int col = nsl + nt * 16 + fr;     // cols>=300 compute to 0
#pragma unroll
            for (int r2 = 0; r2 < 4; ++r2)
                X[(rbase + r2) * XSTR + col] = f2bf(acc0[nt][r2]);
        }
    }
    __syncthreads();

    // ---- Gram mini-GEMM: only the 9 fragments the epilogue reads.
    // wave0: (0,0) diag -> gdiag; waves 1..8: (0,1),(0,2),(0,3),(1,1),(1,3),
    // (2,2),(2,3),(3,3). Store cols 16..59 compact at stride 44.
    if (wave < 9) {
        int mf, nf;
        if (wave == 0)      { mf = 0; nf = 0; }
        else if (wave < 4)  { mf = 0; nf = wave; }
        else if (wave == 4) { mf = 1; nf = 1; }
        else if (wave == 5) { mf = 1; nf = 3; }
        else if (wave == 6) { mf = 2; nf = 2; }
        else if (wave == 7) { mf = 2; nf = 3; }
        else                { mf = 3; nf = 3; }
        f32x4 ga = {};
        for (int k0 = 0; k0 < KPAD; k0 += 32) {
            s16x8 av = *(const s16x8*)&X[(mf * 16 + fr) * XSTR + k0 + fq * 8];
            s16x8 bv = *(const s16x8*)&X[(nf * 16 + fr) * XSTR + k0 + fq * 8];
            ga = __builtin_amdgcn_mfma_f32_16x16x32_bf16(av, bv, ga, 0, 0, 0);
        }
        if (wave == 0) {
#pragma unroll
            for (int r2 = 0; r2 < 4; ++r2)
                if (fr == fq * 4 + r2) gdiag[fr] = ga[r2];
        } else {
            const int col = nf * 16 + fr;
            if (col < 60) {
#pragma unroll
                for (int r2 = 0; r2 < 4; ++r2)
                    GL[(mf * 16 + fq * 4 + r2) * GSTR3 + (col - 16)] = ga[r2];
            }
        }
    }
    __syncthreads();

    // ---- Epilogue: 1 pair per 16-lane quad, 48 quads, 4 rounds (176 pairs).
    // Stats from G; single norm+ELU+dot pass; one 4-step shuffle chain.
    const int quad = lane >> 4, fl = lane & 15;
    const int qq = wave * 4 + quad;            // 0..47
    const float b2v = b2[0];
    const float inv = 1.f / (float)H_DIM;

    for (int round = 0; round < 4; ++round) {
        const int q = round * 48 + qq;          // 0..191
        const int qc = q < NPAIR - 1 ? q : NPAIR - 1;
        const int di = qc / NREL, rr = qc % NREL;
        const int ii = i0 + di, j = ii - KWIN + rr;
        const bool active = (q < NPAIR) && (j >= 0) && (j < L_SEQ);

        const int iA = di;                 // Ae row in X (0..15)
        const int jA = 16 + di + rr;       // Ac row (16..41)
        const int pA = 48 + rr;            // Pb row (48..58)

        const float Se  = GL[iA * GSTR3 + 43];          // col 59 (ones)
        const float Sc  = GL[jA * GSTR3 + 43];
        const float Sp  = GL[pA * GSTR3 + 43];
        const float SSe = gdiag[iA];
        const float SSc = GL[jA * GSTR3 + (jA - 16)];
        const float SSp = GL[pA * GSTR3 + (pA - 16)];
        const float Dec = GL[iA * GSTR3 + (jA - 16)];
        const float Dep = GL[iA * GSTR3 + (pA - 16)];
        const float Dcp = GL[jA * GSTR3 + (pA - 16)];

        const float mu   = (Se + Sc + Sp) * inv;
        const float ss   = SSe + SSc + SSp + 2.f * (Dec + Dep + Dcp);
        const float rsig = rsqrtf(ss * inv - mu * mu + LN_EPS);
        const float nmrs = -mu * rsig;

        const int ea = iA * XSTR, ca = jA * XSTR, pa = pA * XSTR;

        float acc2 = 0.f;
#pragma unroll
        for (int w5 = 0; w5 < 5; ++w5) {
            const int c = w5 * 64 + fl * 4;     // 0..316, zero-padded
            s16x4 a0 = *(const s16x4*)&X[ea + c];
            s16x4 d0 = *(const s16x4*)&X[ca + c];
            s16x4 p0 = *(const s16x4*)&X[pa + c];
            float4 g  = *(const float4*)&SG[c];
            float4 bb = *(const float4*)&SB[c];
            float4 w  = *(const float4*)&SW[c];
#pragma unroll
            for (int e = 0; e < 4; ++e) {
                float v = bf2f(a0[e]) + bf2f(d0[e]) + bf2f(p0[e]);
                float t0 = fmaf(fmaf(v, rsig, nmrs), (&g.x)[e], (&bb.x)[e]);
                t0 = t0 > 0.f ? t0 : __expf(t0) - 1.f;
                acc2 = fmaf(t0, (&w.x)[e], acc2);
            }
        }
#pragma unroll
        for (int off = 1; off < 16; off <<= 1) acc2 += __shfl_xor(acc2, off);

        if (fl == 0 && active) {
            const int jb = ii - KWIN < 0 ? 0 : ii - KWIN;
            const int n = rowstart(ii) + (j - jb);
            out[(size_t)b * NC + n] = acc2 + b2v;
            if (b == 0) {
                posout[2 * (size_t)n]     = (float)(ii + 1);
                posout[2 * (size_t)n + 1] = (float)(j + 1);
            }
        }
    }
}

// ---------------------------------------------------------------------------
extern "C" void kernel_launch(void* const* d_in, const int* in_sizes, int n_in,
                              void* d_out, int out_size, void* d_ws, size_t ws_size,
                              hipStream_t stream) {
    const float* h_e     = (const float*)d_in[0];
    const float* h_c     = (const float*)d_in[1];
    const float* h_share = (const float*)d_in[2];
    // d_in[3] = mask (unused)
    const float* pos_W   = (const float*)d_in[4];
    const float* W1      = (const float*)d_in[5];
    const float* b1      = (const float*)d_in[6];
    const float* ln_g    = (const float*)d_in[7];
    const float* ln_b    = (const float*)d_in[8];
    const float* W2      = (const float*)d_in[9];
    const float* b2      = (const float*)d_in[10];

    float* ws     = (float*)d_ws;
    short* prelbf = (short*)ws;
    short* Wb     = (short*)(ws + WB_OFF);

    float* out    = (float*)d_out;
    float* posout = out + BNC;

    prep_kernel<<<115, 256, 0, stream>>>(pos_W, W1, b1, prelbf, Wb);

    fused_kernel<<<NB * (L_SEQ / ITILE), THREADS, 0, stream>>>(
        h_e, h_c, h_share, Wb, prelbf, ln_g, ln_b, W2, b2, out, posout);
}

// Round 5
// 125.887 us; speedup vs baseline: 1.6715x; 1.1646x over previous
//
#include <hip/hip_runtime.h>
#include <hip/hip_bf16.h>
#include <math.h>

// Problem constants
#define L_SEQ   1024
#define NB      8
#define H_DIM   300
#define KWIN    5
#define NREL    11          // 2K+1
#define PDIM    50
#define NC      11234       // band pair count for L=1024, K=5
#define BNC     (NB*NC)     // 89872
#define LN_EPS  1e-5f

#define KPAD    320         // K padded with zeros in [300,320)
#define WKSTR   320         // Wb k-stride (shorts)
#define WNPAD   320         // Wb padded n rows

#define ITILE   32          // i rows per block
#define NTB     32          // i-tiles per batch
#define THREADS 768         // 12 waves
#define HROWS   42          // hc halo rows: i0-5 .. i0+36
#define XROWS   96          // 0..31 he/Ae (E0,E1), 32..79 hc/Ac (C0,C1,C2;
                            // 74..79 zero), 80..90 Pb, 91 ones, 92..95 zero
#define XSTR    328         // X row stride in shorts
#define NPAIR   (ITILE*NREL)  // 352

// Workspace layout (float offsets)
#define WB_OFF   2048       // prelbf (11*328 shorts = 7216 B) lives at 0
                            // Wb: 2*320*320 shorts = 102400 floats

typedef __attribute__((ext_vector_type(8))) short s16x8;
typedef __attribute__((ext_vector_type(4))) short s16x4;
typedef __attribute__((ext_vector_type(4))) float f32x4;

__device__ __forceinline__ short f2bf(float f) {
    unsigned u = __float_as_uint(f);
    u += 0x7fffu + ((u >> 16) & 1u);
    return (short)(u >> 16);
}
__device__ __forceinline__ float bf2f(short s) {
    return __uint_as_float(((unsigned)(unsigned short)s) << 16);
}

// band row start: first linear index n of row i
__device__ __forceinline__ int rowstart(int i) {
    if (i < 5)     return 6 * i + (i * (i - 1)) / 2;
    if (i <= 1018) return 40 + (i - 5) * 11;
    int d = i - 1019;
    return 11194 + d * 10 - (d * (d - 1)) / 2;
}

// ---------------------------------------------------------------------------
// Kernel 1: prep (unchanged from r4).
__global__ __launch_bounds__(256) void prep_kernel(
    const float* __restrict__ pos_W, const float* __restrict__ W1,
    const float* __restrict__ b1, short* __restrict__ prelbf,
    short* __restrict__ Wb)
{
    if (blockIdx.x < 15) {
        __shared__ float semb[NREL * PDIM];
        for (int t = threadIdx.x; t < NREL * PDIM; t += 256) {
            int r = t / PDIM, d = t % PDIM;
            float acc = 0.f;
#pragma unroll
            for (int r2 = 0; r2 < NREL; ++r2) {
                float cnt = (float)(L_SEQ - abs(r2 - KWIN));
                int dr = r - r2;
                acc += cnt * expf(-(float)(dr * dr)) * pos_W[r2 * PDIM + d];
            }
            semb[t] = acc;
        }
        __syncthreads();
        int t = blockIdx.x * 256 + threadIdx.x;
        if (t < NREL * XSTR) {
            int r = t / XSTR, h = t % XSTR;
            float acc = 0.f;
            if (h < H_DIM) {
                acc = b1[h];
                const float* wrow = W1 + (size_t)h * 650 + 600;
                const float* em = semb + r * PDIM;
#pragma unroll 10
                for (int d = 0; d < PDIM; ++d) acc += wrow[d] * em[d];
            }
            prelbf[t] = (h < H_DIM) ? f2bf(acc) : (short)0;
        }
    } else {
        // 2*320*320 shorts = 25600 s16x8 chunks over 100 blocks
        int c = (blockIdx.x - 15) * 256 + threadIdx.x;
        if (c < 25600) {
            int z   = c / 12800;
            int rem = c - z * 12800;
            int n   = rem / 40;
            int k0  = (rem - n * 40) * 8;
            s16x8 v8 = (s16x8){0,0,0,0,0,0,0,0};
            if (n < H_DIM) {
                const float* base = W1 + (size_t)n * 650 + z * H_DIM;
#pragma unroll
                for (int e = 0; e < 8; ++e) {
                    int k = k0 + e;
                    float v = 0.f;
                    if (k < H_DIM) v = base[k];
                    v8[e] = f2bf(v);
                }
            }
            *(s16x8*)&Wb[(size_t)c * 8] = v8;
        }
    }
}

// ---------------------------------------------------------------------------
// Kernel 2: fused GEMM + Gram + epilogue. Block = (b, i-tile of 32),
// 768 threads (12 waves), grid 256 (1 block/CU).
// Wb read exactly ONCE per block (400 KB, the structural floor):
// waves 0-3: E-half x N-slice, tiles E0+E1 (10 MFMA / 5 B-loads);
// waves 4-7: C-half x N-slice, tiles C0+C1+C2 (15 MFMA / 5 B-loads);
// wave 8: P.P Gram concurrent with GEMM; waves 9-11 idle until Gram.
// NO min-waves launch_bounds (r1-r3 proved caps -> catastrophic spills).
__global__ __launch_bounds__(THREADS) void fused_kernel(
    const float* __restrict__ h_e, const float* __restrict__ h_c,
    const float* __restrict__ h_share, const short* __restrict__ Wb,
    const short* __restrict__ prelbf,
    const float* __restrict__ ln_g, const float* __restrict__ ln_b,
    const float* __restrict__ W2, const float* __restrict__ b2,
    float* __restrict__ out, float* __restrict__ posout)
{
    __shared__ __align__(16) short X[XROWS * XSTR];   // 62976 B
    __shared__ __align__(16) float GL[9 * 272];       // 9792 B (9 full frags)
    __shared__ __align__(16) float SSeA[32];
    __shared__ __align__(16) float SScA[48];
    __shared__ __align__(16) float SSpA[16];
    __shared__ __align__(16) float SpA[16];
    __shared__ __align__(16) float SG[320];
    __shared__ __align__(16) float SB[320];
    __shared__ __align__(16) float SW[320];

    const int tid = threadIdx.x;
    const int b   = blockIdx.x >> 5;          // 32 i-tiles per batch
    const int i0  = (blockIdx.x & 31) * ITILE;

    // ---- zero-fill: rows 74..79 & 92..95 full width (10*41) + rows 0..73
    // cols [304,328) (74*3) = 632 16B chunks
    for (int t = tid; t < 632; t += THREADS) {
        int row, c;
        if (t < 410) { int rr2 = t / 41; row = rr2 < 6 ? 74 + rr2 : 92 + (rr2 - 6); c = (t % 41) * 8; }
        else         { int u = t - 410; row = u / 3; c = 304 + (u % 3) * 8; }
        *(s16x8*)&X[row * XSTR + c] = (s16x8){0,0,0,0,0,0,0,0};
    }
    // ---- ones row (91): bf16(1.0)=0x3F80 for cols<300, else 0
    for (int t = tid; t < XSTR; t += THREADS)
        X[91 * XSTR + t] = (t < H_DIM) ? (short)0x3F80 : (short)0;
    // ---- Pb rows 80..90: straight copy from prelbf (layout matches)
    for (int t = tid; t < NREL * 41; t += THREADS) {
        int r = t / 41, c = (t % 41) * 8;
        *(s16x8*)&X[(80 + r) * XSTR + c] = *(const s16x8*)(prelbf + r * XSTR + c);
    }
    // ---- LN params to LDS (zero pad to 320)
    if (tid < 320) {
        bool v = tid < H_DIM;
        SG[tid] = v ? ln_g[tid] : 0.f;
        SB[tid] = v ? ln_b[tid] : 0.f;
        SW[tid] = v ? W2[tid]   : 0.f;
    }
    // ---- stage 42 halo rows; h_share read once per row.
    for (int t = tid; t < HROWS * 76; t += THREADS) {
        int s = t / 76, kc = (t % 76) * 4;
        int g = i0 - KWIN + s;
        bool valid = (kc < H_DIM) && (g >= 0) && (g < L_SEQ);
        float4 hs4 = make_float4(0.f,0.f,0.f,0.f), hc4 = hs4;
        size_t off = 0;
        if (valid) {
            off = ((size_t)b * L_SEQ + g) * H_DIM + kc;
            hs4 = *(const float4*)(h_share + off);
            hc4 = *(const float4*)(h_c + off);
        }
        s16x4 vc = { f2bf(hc4.x + hs4.x), f2bf(hc4.y + hs4.y),
                     f2bf(hc4.z + hs4.z), f2bf(hc4.w + hs4.w) };
        *(s16x4*)&X[(32 + s) * XSTR + kc] = vc;
        if (s >= KWIN && s < KWIN + ITILE) {   // he row: g = i0 + (s-5)
            float4 he4 = make_float4(0.f,0.f,0.f,0.f);
            if (valid) he4 = *(const float4*)(h_e + off);
            s16x4 ve = { f2bf(he4.x + hs4.x), f2bf(he4.y + hs4.y),
                         f2bf(he4.z + hs4.z), f2bf(he4.w + hs4.w) };
            *(s16x4*)&X[(s - KWIN) * XSTR + kc] = ve;
        }
    }
    __syncthreads();

    // ---- Main GEMM (waves 0..7) + PP Gram (wave 8).
    const int wave = tid >> 6, lane = tid & 63;
    const int fr = lane & 15, fq = lane >> 4;
    const bool isE = wave < 4;
    const int nsl = (wave & 3) * 80;
    const short* wbase = Wb + ((size_t)((isE ? 0 : WNPAD) + nsl + fr)) * WKSTR + fq * 8;
    const int arow0 = (isE ? 0 : 32) + fr;     // E0 or C0

    f32x4 acc0[5] = {};
    f32x4 acc1[5] = {};
    f32x4 acc2[5] = {};

    if (wave < 8) {
        for (int k0 = 0; k0 < KPAD; k0 += 32) {
            s16x8 bf[5];
#pragma unroll
            for (int nt = 0; nt < 5; ++nt)
                bf[nt] = *(const s16x8*)(wbase + (size_t)nt * 16 * WKSTR + k0);
            s16x8 af0 = *(const s16x8*)&X[arow0 * XSTR + k0 + fq * 8];
            s16x8 af1 = *(const s16x8*)&X[(arow0 + 16) * XSTR + k0 + fq * 8];
#pragma unroll
            for (int nt = 0; nt < 5; ++nt)
                acc0[nt] = __builtin_amdgcn_mfma_f32_16x16x32_bf16(af0, bf[nt], acc0[nt], 0, 0, 0);
#pragma unroll
            for (int nt = 0; nt < 5; ++nt)
                acc1[nt] = __builtin_amdgcn_mfma_f32_16x16x32_bf16(af1, bf[nt], acc1[nt], 0, 0, 0);
            if (!isE) {
                s16x8 af2 = *(const s16x8*)&X[(arow0 + 32) * XSTR + k0 + fq * 8];
#pragma unroll
                for (int nt = 0; nt < 5; ++nt)
                    acc2[nt] = __builtin_amdgcn_mfma_f32_16x16x32_bf16(af2, bf[nt], acc2[nt], 0, 0, 0);
            }
        }
    } else if (wave == 8) {
        // P.P Gram (rows 80..95): only depends on staged Pb/ones rows.
        f32x4 gp = {};
        for (int k0 = 0; k0 < KPAD; k0 += 32) {
            s16x8 av = *(const s16x8*)&X[(80 + fr) * XSTR + k0 + fq * 8];
            gp = __builtin_amdgcn_mfma_f32_16x16x32_bf16(av, av, gp, 0, 0, 0);
        }
#pragma unroll
        for (int r2 = 0; r2 < 4; ++r2) {
            if (fr == fq * 4 + r2) SSpA[fr] = gp[r2];
            if (fr == 11)          SpA[fq * 4 + r2] = gp[r2];
        }
    }
    __syncthreads();   // all waves done reading X he/hc inputs

    // ---- write Ae/Ac into X (bf16). C/D: col = nsl+nt*16+fr, row = fq*4+r2.
    if (wave < 8) {
        const int rbase = (isE ? 0 : 32) + fq * 4;
#pragma unroll
        for (int nt = 0; nt < 5; ++nt) {
            const int col = nsl + nt * 16 + fr;     // cols>=300 compute to 0
#pragma unroll
            for (int r2 = 0; r2 < 4; ++r2) {
                X[(rbase + r2) * XSTR + col]      = f2bf(acc0[nt][r2]);
                X[(rbase + 16 + r2) * XSTR + col] = f2bf(acc1[nt][r2]);
            }
            if (!isE) {
#pragma unroll
                for (int r2 = 0; r2 < 4; ++r2)
                    X[(rbase + 32 + r2) * XSTR + col] = f2bf(acc2[nt][r2]);
            }
        }
    }
    __syncthreads();

    // ---- Gram: the 15 needed fragments over 96 rows (k=320).
    // Tiles: E0=0,E1=16,C0=32,C1=48,C2=64,P=80.
    // waves 0..8 full frags: EC {(0,32),(0,48),(16,48),(16,64)},
    // EP {(0,80),(16,80)}, CP {(32,80),(48,80),(64,80)} -> GL[w].
    // wave 9: E0E0+E1E1 diag -> SSeA; wave 10: C0C0+C1C1 -> SScA;
    // wave 11: C2C2 -> SScA+32. (PP done by wave 8 earlier.)
    if (wave < 9) {
        int mrow, nrow;
        if (wave < 2)       { mrow = 0;                nrow = 32 + 16 * wave; }
        else if (wave == 2) { mrow = 16;               nrow = 48; }
        else if (wave == 3) { mrow = 16;               nrow = 64; }
        else if (wave < 6)  { mrow = 16 * (wave - 4);  nrow = 80; }
        else                { mrow = 32 + 16 * (wave - 6); nrow = 80; }
        f32x4 ga = {};
        for (int k0 = 0; k0 < KPAD; k0 += 32) {
            s16x8 av = *(const s16x8*)&X[(mrow + fr) * XSTR + k0 + fq * 8];
            s16x8 bv = *(const s16x8*)&X[(nrow + fr) * XSTR + k0 + fq * 8];
            ga = __builtin_amdgcn_mfma_f32_16x16x32_bf16(av, bv, ga, 0, 0, 0);
        }
#pragma unroll
        for (int r2 = 0; r2 < 4; ++r2)
            GL[wave * 272 + (fq * 4 + r2) * 17 + fr] = ga[r2];
    } else {
        const int njob = (wave == 11) ? 1 : 2;
        for (int jj = 0; jj < njob; ++jj) {
            const int rbase = (wave == 9) ? 16 * jj : (wave == 10 ? 32 + 16 * jj : 64);
            float* dst = (wave == 9) ? (SSeA + 16 * jj)
                                     : (wave == 10 ? SScA + 16 * jj : SScA + 32);
            f32x4 ga = {};
            for (int k0 = 0; k0 < KPAD; k0 += 32) {
                s16x8 av = *(const s16x8*)&X[(rbase + fr) * XSTR + k0 + fq * 8];
                ga = __builtin_amdgcn_mfma_f32_16x16x32_bf16(av, av, ga, 0, 0, 0);
            }
#pragma unroll
            for (int r2 = 0; r2 < 4; ++r2)
                if (fr == fq * 4 + r2) dst[fr] = ga[r2];
        }
    }
    __syncthreads();

    // ---- Epilogue: 1 pair per 16-lane quad, 48 quads, 8 rounds (352 pairs).
    const int quad = lane >> 4, fl = lane & 15;
    const int qq = wave * 4 + quad;            // 0..47
    const float b2v = b2[0];
    const float inv = 1.f / (float)H_DIM;

    for (int round = 0; round < 8; ++round) {
        const int q = round * 48 + qq;          // 0..383
        const int qc = q < NPAIR - 1 ? q : NPAIR - 1;
        const int di = qc / NREL, rr = qc % NREL;
        const int ii = i0 + di, j = ii - KWIN + rr;
        const bool active = (q < NPAIR) && (j >= 0) && (j < L_SEQ);

        const int Et = di >> 4, et = di & 15;
        const int hidx = di + rr;               // 0..41
        const int Ct = hidx >> 4, ct = hidx & 15;
        const int fEC = Et ? (1 + Ct) : Ct;     // (0,32)(0,48)(16,48)(16,64)

        const float Dec = GL[fEC * 272 + et * 17 + ct];
        const float Dep = GL[(4 + Et) * 272 + et * 17 + rr];
        const float Se  = GL[(4 + Et) * 272 + et * 17 + 11];
        const float Dcp = GL[(6 + Ct) * 272 + ct * 17 + rr];
        const float Sc  = GL[(6 + Ct) * 272 + ct * 17 + 11];
        const float SSe = SSeA[di];
        const float SSc = SScA[hidx];
        const float SSp = SSpA[rr];
        const float Sp  = SpA[rr];

        const float mu   = (Se + Sc + Sp) * inv;
        const float ss   = SSe + SSc + SSp + 2.f * (Dec + Dep + Dcp);
        const float rsig = rsqrtf(ss * inv - mu * mu + LN_EPS);
        const float nmrs = -mu * rsig;

        const int ea = di * XSTR;               // Ae row
        const int ca = (32 + hidx) * XSTR;      // Ac row
        const int pa = (80 + rr) * XSTR;        // Pb row

        float acc2e = 0.f;
#pragma unroll
        for (int w5 = 0; w5 < 5; ++w5) {
            const int c = w5 * 64 + fl * 4;     // 0..316, zero-padded
            s16x4 a0 = *(const s16x4*)&X[ea + c];
            s16x4 d0 = *(const s16x4*)&X[ca + c];
            s16x4 p0 = *(const s16x4*)&X[pa + c];
            float4 g  = *(const float4*)&SG[c];
            float4 bb = *(const float4*)&SB[c];
            float4 w  = *(const float4*)&SW[c];
#pragma unroll
            for (int e = 0; e < 4; ++e) {
                float v = bf2f(a0[e]) + bf2f(d0[e]) + bf2f(p0[e]);
                float t0 = fmaf(fmaf(v, rsig, nmrs), (&g.x)[e], (&bb.x)[e]);
                t0 = t0 > 0.f ? t0 : __expf(t0) - 1.f;
                acc2e = fmaf(t0, (&w.x)[e], acc2e);
            }
        }
#pragma unroll
        for (int off = 1; off < 16; off <<= 1) acc2e += __shfl_xor(acc2e, off);

        if (fl == 0 && active) {
            const int jb = ii - KWIN < 0 ? 0 : ii - KWIN;
            const int n = rowstart(ii) + (j - jb);
            out[(size_t)b * NC + n] = acc2e + b2v;
            if (b == 0) {
                posout[2 * (size_t)n]     = (float)(ii + 1);
                posout[2 * (size_t)n + 1] = (float)(j + 1);
            }
        }
    }
}

// ---------------------------------------------------------------------------
extern "C" void kernel_launch(void* const* d_in, const int* in_sizes, int n_in,
                              void* d_out, int out_size, void* d_ws, size_t ws_size,
                              hipStream_t stream) {
    const float* h_e     = (const float*)d_in[0];
    const float* h_c     = (const float*)d_in[1];
    const float* h_share = (const float*)d_in[2];
    // d_in[3] = mask (unused)
    const float* pos_W   = (const float*)d_in[4];
    const float* W1      = (const float*)d_in[5];
    const float* b1      = (const float*)d_in[6];
    const float* ln_g    = (const float*)d_in[7];
    const float* ln_b    = (const float*)d_in[8];
    const float* W2      = (const float*)d_in[9];
    const float* b2      = (const float*)d_in[10];

    float* ws     = (float*)d_ws;
    short* prelbf = (short*)ws;
    short* Wb     = (short*)(ws + WB_OFF);

    float* out    = (float*)d_out;
    float* posout = out + BNC;

    prep_kernel<<<115, 256, 0, stream>>>(pos_W, W1, b1, prelbf, Wb);

    fused_kernel<<<NB * NTB, THREADS, 0, stream>>>(
        h_e, h_c, h_share, Wb, prelbf, ln_g, ln_b, W2, b2, out, posout);
}

// Round 6
// 124.061 us; speedup vs baseline: 1.6961x; 1.0147x over previous
//
#include <hip/hip_runtime.h>
#include <hip/hip_bf16.h>
#include <math.h>

// Problem constants
#define L_SEQ   1024
#define NB      8
#define H_DIM   300
#define KWIN    5
#define NREL    11          // 2K+1
#define PDIM    50
#define NC      11234       // band pair count for L=1024, K=5
#define BNC     (NB*NC)     // 89872
#define LN_EPS  1e-5f

#define KPAD    320         // K padded with zeros in [300,320)
#define WKSTR   320         // Wb k-stride (shorts)
#define WNPAD   320         // Wb padded n rows

#define ITILE   32          // i rows per block
#define NTB     32          // i-tiles per batch
#define THREADS 1024        // 16 waves
#define HROWS   42          // hc halo rows: i0-5 .. i0+36
#define XROWS   96          // 0..31 he/Ae (E0,E1), 32..79 hc/Ac (C0,C1,C2;
                            // 74..79 zero), 80..90 Pb, 91 ones, 92..95 zero
#define XSTR    328         // X row stride in shorts
#define NPAIR   (ITILE*NREL)  // 352

// Workspace layout (float offsets)
#define WB_OFF   2048       // prelbf (11*328 shorts = 7216 B) lives at 0
                            // Wb: 2*320*320 shorts = 102400 floats

typedef __attribute__((ext_vector_type(8))) short s16x8;
typedef __attribute__((ext_vector_type(4))) short s16x4;
typedef __attribute__((ext_vector_type(4))) float f32x4;

__device__ __forceinline__ short f2bf(float f) {
    unsigned u = __float_as_uint(f);
    u += 0x7fffu + ((u >> 16) & 1u);
    return (short)(u >> 16);
}
__device__ __forceinline__ float bf2f(short s) {
    return __uint_as_float(((unsigned)(unsigned short)s) << 16);
}

// band row start: first linear index n of row i
__device__ __forceinline__ int rowstart(int i) {
    if (i < 5)     return 6 * i + (i * (i - 1)) / 2;
    if (i <= 1018) return 40 + (i - 5) * 11;
    int d = i - 1019;
    return 11194 + d * 10 - (d * (d - 1)) / 2;
}

// ---------------------------------------------------------------------------
// Kernel 1: prep (unchanged).
__global__ __launch_bounds__(256) void prep_kernel(
    const float* __restrict__ pos_W, const float* __restrict__ W1,
    const float* __restrict__ b1, short* __restrict__ prelbf,
    short* __restrict__ Wb)
{
    if (blockIdx.x < 15) {
        __shared__ float semb[NREL * PDIM];
        for (int t = threadIdx.x; t < NREL * PDIM; t += 256) {
            int r = t / PDIM, d = t % PDIM;
            float acc = 0.f;
#pragma unroll
            for (int r2 = 0; r2 < NREL; ++r2) {
                float cnt = (float)(L_SEQ - abs(r2 - KWIN));
                int dr = r - r2;
                acc += cnt * expf(-(float)(dr * dr)) * pos_W[r2 * PDIM + d];
            }
            semb[t] = acc;
        }
        __syncthreads();
        int t = blockIdx.x * 256 + threadIdx.x;
        if (t < NREL * XSTR) {
            int r = t / XSTR, h = t % XSTR;
            float acc = 0.f;
            if (h < H_DIM) {
                acc = b1[h];
                const float* wrow = W1 + (size_t)h * 650 + 600;
                const float* em = semb + r * PDIM;
#pragma unroll 10
                for (int d = 0; d < PDIM; ++d) acc += wrow[d] * em[d];
            }
            prelbf[t] = (h < H_DIM) ? f2bf(acc) : (short)0;
        }
    } else {
        // 2*320*320 shorts = 25600 s16x8 chunks over 100 blocks
        int c = (blockIdx.x - 15) * 256 + threadIdx.x;
        if (c < 25600) {
            int z   = c / 12800;
            int rem = c - z * 12800;
            int n   = rem / 40;
            int k0  = (rem - n * 40) * 8;
            s16x8 v8 = (s16x8){0,0,0,0,0,0,0,0};
            if (n < H_DIM) {
                const float* base = W1 + (size_t)n * 650 + z * H_DIM;
#pragma unroll
                for (int e = 0; e < 8; ++e) {
                    int k = k0 + e;
                    float v = 0.f;
                    if (k < H_DIM) v = base[k];
                    v8[e] = f2bf(v);
                }
            }
            *(s16x8*)&Wb[(size_t)c * 8] = v8;
        }
    }
}

// ---------------------------------------------------------------------------
// Kernel 2: fused GEMM + Gram + epilogue. Block = (b, i-tile of 32),
// 1024 threads (16 waves = 4/SIMD), grid 256 (1 block/CU).
// Wb read exactly ONCE per block (400 KB, the structural floor), now spread
// over 12 GEMM waves (E: 4 waves x 10 MFMA/kstep; C: 8 waves, N-subsliced,
// 9 or 6 MFMA/kstep). wave 12: P.P Gram concurrent with GEMM.
// Single f32x4 acc[10] shared across exclusive wave branches, all indices
// compile-time (no scratch). NO min-waves launch_bounds (spill trigger).
__global__ __launch_bounds__(THREADS) void fused_kernel(
    const float* __restrict__ h_e, const float* __restrict__ h_c,
    const float* __restrict__ h_share, const short* __restrict__ Wb,
    const short* __restrict__ prelbf,
    const float* __restrict__ ln_g, const float* __restrict__ ln_b,
    const float* __restrict__ W2, const float* __restrict__ b2,
    float* __restrict__ out, float* __restrict__ posout)
{
    __shared__ __align__(16) short X[XROWS * XSTR];   // 62976 B
    __shared__ __align__(16) float GL[9 * 272];       // 9792 B (9 full frags)
    __shared__ __align__(16) float SSeA[32];
    __shared__ __align__(16) float SScA[48];
    __shared__ __align__(16) float SSpA[16];
    __shared__ __align__(16) float SpA[16];
    __shared__ __align__(16) float SG[320];
    __shared__ __align__(16) float SB[320];
    __shared__ __align__(16) float SW[320];

    const int tid = threadIdx.x;
    const int b   = blockIdx.x >> 5;          // 32 i-tiles per batch
    const int i0  = (blockIdx.x & 31) * ITILE;

    // ---- zero-fill: rows 74..79 & 92..95 full width (10*41) + rows 0..73
    // cols [304,328) (74*3) = 632 16B chunks
    for (int t = tid; t < 632; t += THREADS) {
        int row, c;
        if (t < 410) { int rr2 = t / 41; row = rr2 < 6 ? 74 + rr2 : 92 + (rr2 - 6); c = (t % 41) * 8; }
        else         { int u = t - 410; row = u / 3; c = 304 + (u % 3) * 8; }
        *(s16x8*)&X[row * XSTR + c] = (s16x8){0,0,0,0,0,0,0,0};
    }
    // ---- ones row (91): bf16(1.0)=0x3F80 for cols<300, else 0
    for (int t = tid; t < XSTR; t += THREADS)
        X[91 * XSTR + t] = (t < H_DIM) ? (short)0x3F80 : (short)0;
    // ---- Pb rows 80..90: straight copy from prelbf (layout matches)
    for (int t = tid; t < NREL * 41; t += THREADS) {
        int r = t / 41, c = (t % 41) * 8;
        *(s16x8*)&X[(80 + r) * XSTR + c] = *(const s16x8*)(prelbf + r * XSTR + c);
    }
    // ---- LN params to LDS (zero pad to 320)
    if (tid < 320) {
        bool v = tid < H_DIM;
        SG[tid] = v ? ln_g[tid] : 0.f;
        SB[tid] = v ? ln_b[tid] : 0.f;
        SW[tid] = v ? W2[tid]   : 0.f;
    }
    // ---- stage 42 halo rows; h_share read once per row.
    for (int t = tid; t < HROWS * 76; t += THREADS) {
        int s = t / 76, kc = (t % 76) * 4;
        int g = i0 - KWIN + s;
        bool valid = (kc < H_DIM) && (g >= 0) && (g < L_SEQ);
        float4 hs4 = make_float4(0.f,0.f,0.f,0.f), hc4 = hs4;
        size_t off = 0;
        if (valid) {
            off = ((size_t)b * L_SEQ + g) * H_DIM + kc;
            hs4 = *(const float4*)(h_share + off);
            hc4 = *(const float4*)(h_c + off);
        }
        s16x4 vc = { f2bf(hc4.x + hs4.x), f2bf(hc4.y + hs4.y),
                     f2bf(hc4.z + hs4.z), f2bf(hc4.w + hs4.w) };
        *(s16x4*)&X[(32 + s) * XSTR + kc] = vc;
        if (s >= KWIN && s < KWIN + ITILE) {   // he row: g = i0 + (s-5)
            float4 he4 = make_float4(0.f,0.f,0.f,0.f);
            if (valid) he4 = *(const float4*)(h_e + off);
            s16x4 ve = { f2bf(he4.x + hs4.x), f2bf(he4.y + hs4.y),
                         f2bf(he4.z + hs4.z), f2bf(he4.w + hs4.w) };
            *(s16x4*)&X[(s - KWIN) * XSTR + kc] = ve;
        }
    }
    __syncthreads();

    // ---- Main GEMM (waves 0..11) + PP Gram (wave 12).
    const int wave = tid >> 6, lane = tid & 63;
    const int fr = lane & 15, fq = lane >> 4;

    f32x4 acc[10] = {};

    if (wave < 4) {
        // E-half: slice = wave, 5 ntiles, M tiles E0(rows 0..15), E1(16..31).
        const int nsl = wave * 80;
        const short* wbase = Wb + ((size_t)(nsl + fr)) * WKSTR + fq * 8;
        const int arow0 = fr;
        for (int k0 = 0; k0 < KPAD; k0 += 32) {
            s16x8 bf[5];
#pragma unroll
            for (int nt = 0; nt < 5; ++nt)
                bf[nt] = *(const s16x8*)(wbase + (size_t)nt * 16 * WKSTR + k0);
            s16x8 a0 = *(const s16x8*)&X[arow0 * XSTR + k0 + fq * 8];
            s16x8 a1 = *(const s16x8*)&X[(arow0 + 16) * XSTR + k0 + fq * 8];
#pragma unroll
            for (int nt = 0; nt < 5; ++nt)
                acc[nt] = __builtin_amdgcn_mfma_f32_16x16x32_bf16(a0, bf[nt], acc[nt], 0, 0, 0);
#pragma unroll
            for (int nt = 0; nt < 5; ++nt)
                acc[5 + nt] = __builtin_amdgcn_mfma_f32_16x16x32_bf16(a1, bf[nt], acc[5 + nt], 0, 0, 0);
        }
    } else if (wave < 12) {
        // C-half: slice p = (wave-4)>>1, sub = (wave-4)&1.
        // sub0: ntiles 0..2 (9 MFMA); sub1: ntiles 3..4 (6 MFMA).
        // M tiles C0(32..47), C1(48..63), C2(64..79).
        const int p = (wave - 4) >> 1;
        const int sub = (wave - 4) & 1;
        const int nsl = p * 80;
        const int arow0 = 32 + fr;
        if (sub == 0) {
            const short* wbase = Wb + ((size_t)(WNPAD + nsl + fr)) * WKSTR + fq * 8;
            for (int k0 = 0; k0 < KPAD; k0 += 32) {
                s16x8 bf[3];
#pragma unroll
                for (int nt = 0; nt < 3; ++nt)
                    bf[nt] = *(const s16x8*)(wbase + (size_t)nt * 16 * WKSTR + k0);
#pragma unroll
                for (int m = 0; m < 3; ++m) {
                    s16x8 am = *(const s16x8*)&X[(arow0 + 16 * m) * XSTR + k0 + fq * 8];
#pragma unroll
                    for (int nt = 0; nt < 3; ++nt)
                        acc[m * 3 + nt] = __builtin_amdgcn_mfma_f32_16x16x32_bf16(am, bf[nt], acc[m * 3 + nt], 0, 0, 0);
                }
            }
        } else {
            const short* wbase = Wb + ((size_t)(WNPAD + nsl + 48 + fr)) * WKSTR + fq * 8;
            for (int k0 = 0; k0 < KPAD; k0 += 32) {
                s16x8 bf[2];
#pragma unroll
                for (int nt = 0; nt < 2; ++nt)
                    bf[nt] = *(const s16x8*)(wbase + (size_t)nt * 16 * WKSTR + k0);
#pragma unroll
                for (int m = 0; m < 3; ++m) {
                    s16x8 am = *(const s16x8*)&X[(arow0 + 16 * m) * XSTR + k0 + fq * 8];
#pragma unroll
                    for (int nt = 0; nt < 2; ++nt)
                        acc[m * 2 + nt] = __builtin_amdgcn_mfma_f32_16x16x32_bf16(am, bf[nt], acc[m * 2 + nt], 0, 0, 0);
                }
            }
        }
    } else if (wave == 12) {
        // P.P Gram (rows 80..95): only depends on staged Pb/ones rows.
        f32x4 gp = {};
        for (int k0 = 0; k0 < KPAD; k0 += 32) {
            s16x8 av = *(const s16x8*)&X[(80 + fr) * XSTR + k0 + fq * 8];
            gp = __builtin_amdgcn_mfma_f32_16x16x32_bf16(av, av, gp, 0, 0, 0);
        }
#pragma unroll
        for (int r2 = 0; r2 < 4; ++r2) {
            if (fr == fq * 4 + r2) SSpA[fr] = gp[r2];
            if (fr == 11)          SpA[fq * 4 + r2] = gp[r2];
        }
    }
    __syncthreads();   // all waves done reading X he/hc inputs

    // ---- write Ae/Ac into X (bf16). C/D: col = nsl+nt*16+fr, row = fq*4+r2.
    if (wave < 4) {
        const int nsl = wave * 80;
#pragma unroll
        for (int nt = 0; nt < 5; ++nt) {
            const int col = nsl + nt * 16 + fr;     // cols>=300 compute to 0
#pragma unroll
            for (int r2 = 0; r2 < 4; ++r2) {
                X[(fq * 4 + r2) * XSTR + col]      = f2bf(acc[nt][r2]);
                X[(16 + fq * 4 + r2) * XSTR + col] = f2bf(acc[5 + nt][r2]);
            }
        }
    } else if (wave < 12) {
        const int p = (wave - 4) >> 1;
        const int sub = (wave - 4) & 1;
        const int nsl = p * 80;
        if (sub == 0) {
#pragma unroll
            for (int nt = 0; nt < 3; ++nt) {
                const int col = nsl + nt * 16 + fr;
#pragma unroll
                for (int m = 0; m < 3; ++m)
#pragma unroll
                    for (int r2 = 0; r2 < 4; ++r2)
                        X[(32 + m * 16 + fq * 4 + r2) * XSTR + col] = f2bf(acc[m * 3 + nt][r2]);
            }
        } else {
#pragma unroll
            for (int nt = 0; nt < 2; ++nt) {
                const int col = nsl + 48 + nt * 16 + fr;
#pragma unroll
                for (int m = 0; m < 3; ++m)
#pragma unroll
                    for (int r2 = 0; r2 < 4; ++r2)
                        X[(32 + m * 16 + fq * 4 + r2) * XSTR + col] = f2bf(acc[m * 2 + nt][r2]);
            }
        }
    }
    __syncthreads();

    // ---- Gram: the 15 needed fragments over 96 rows (k=320).
    // Tiles: E0=0,E1=16,C0=32,C1=48,C2=64,P=80.
    // waves 0..8 full frags: EC {(0,32),(0,48),(16,48),(16,64)},
    // EP {(0,80),(16,80)}, CP {(32,80),(48,80),(64,80)} -> GL[w].
    // diag (1 job/wave): 9:E0->SSeA, 10:E1->SSeA+16, 11:C0->SScA,
    // 13:C1->SScA+16, 14:C2->SScA+32. (PP by wave 12 earlier.)
    if (wave < 9) {
        int mrow, nrow;
        if (wave < 2)       { mrow = 0;                nrow = 32 + 16 * wave; }
        else if (wave == 2) { mrow = 16;               nrow = 48; }
        else if (wave == 3) { mrow = 16;               nrow = 64; }
        else if (wave < 6)  { mrow = 16 * (wave - 4);  nrow = 80; }
        else                { mrow = 32 + 16 * (wave - 6); nrow = 80; }
        f32x4 ga = {};
        for (int k0 = 0; k0 < KPAD; k0 += 32) {
            s16x8 av = *(const s16x8*)&X[(mrow + fr) * XSTR + k0 + fq * 8];
            s16x8 bv = *(const s16x8*)&X[(nrow + fr) * XSTR + k0 + fq * 8];
            ga = __builtin_amdgcn_mfma_f32_16x16x32_bf16(av, bv, ga, 0, 0, 0);
        }
#pragma unroll
        for (int r2 = 0; r2 < 4; ++r2)
            GL[wave * 272 + (fq * 4 + r2) * 17 + fr] = ga[r2];
    } else if (wave == 9 || wave == 10 || wave == 11 || wave == 13 || wave == 14) {
        int rbase;
        float* dst;
        if (wave == 9)       { rbase = 0;  dst = SSeA; }
        else if (wave == 10) { rbase = 16; dst = SSeA + 16; }
        else if (wave == 11) { rbase = 32; dst = SScA; }
        else if (wave == 13) { rbase = 48; dst = SScA + 16; }
        else                 { rbase = 64; dst = SScA + 32; }
        f32x4 ga = {};
        for (int k0 = 0; k0 < KPAD; k0 += 32) {
            s16x8 av = *(const s16x8*)&X[(rbase + fr) * XSTR + k0 + fq * 8];
            ga = __builtin_amdgcn_mfma_f32_16x16x32_bf16(av, av, ga, 0, 0, 0);
        }
#pragma unroll
        for (int r2 = 0; r2 < 4; ++r2)
            if (fr == fq * 4 + r2) dst[fr] = ga[r2];
    }
    __syncthreads();

    // ---- Epilogue: 1 pair per 16-lane quad, 64 quads, 6 rounds (352 pairs).
    const int quad = lane >> 4, fl = lane & 15;
    const int qq = wave * 4 + quad;            // 0..63
    const float b2v = b2[0];
    const float inv = 1.f / (float)H_DIM;

    for (int round = 0; round < 6; ++round) {
        const int q = round * 64 + qq;          // 0..383
        const int qc = q < NPAIR - 1 ? q : NPAIR - 1;
        const int di = qc / NREL, rr = qc % NREL;
        const int ii = i0 + di, j = ii - KWIN + rr;
        const bool active = (q < NPAIR) && (j >= 0) && (j < L_SEQ);

        const int Et = di >> 4, et = di & 15;
        const int hidx = di + rr;               // 0..41
        const int Ct = hidx >> 4, ct = hidx & 15;
        const int fEC = Et ? (1 + Ct) : Ct;     // (0,32)(0,48)(16,48)(16,64)

        const float Dec = GL[fEC * 272 + et * 17 + ct];
        const float Dep = GL[(4 + Et) * 272 + et * 17 + rr];
        const float Se  = GL[(4 + Et) * 272 + et * 17 + 11];
        const float Dcp = GL[(6 + Ct) * 272 + ct * 17 + rr];
        const float Sc  = GL[(6 + Ct) * 272 + ct * 17 + 11];
        const float SSe = SSeA[di];
        const float SSc = SScA[hidx];
        const float SSp = SSpA[rr];
        const float Sp  = SpA[rr];

        const float mu   = (Se + Sc + Sp) * inv;
        const float ss   = SSe + SSc + SSp + 2.f * (Dec + Dep + Dcp);
        const float rsig = rsqrtf(ss * inv - mu * mu + LN_EPS);
        const float nmrs = -mu * rsig;

        const int ea = di * XSTR;               // Ae row
        const int ca = (32 + hidx) * XSTR;      // Ac row
        const int pa = (80 + rr) * XSTR;        // Pb row

        float acc2e = 0.f;
#pragma unroll
        for (int w5 = 0; w5 < 5; ++w5) {
            const int c = w5 * 64 + fl * 4;     // 0..316, zero-padded
            s16x4 a0 = *(const s16x4*)&X[ea + c];
            s16x4 d0 = *(const s16x4*)&X[ca + c];
            s16x4 p0 = *(const s16x4*)&X[pa + c];
            float4 g  = *(const float4*)&SG[c];
            float4 bb = *(const float4*)&SB[c];
            float4 w  = *(const float4*)&SW[c];
#pragma unroll
            for (int e = 0; e < 4; ++e) {
                float v = bf2f(a0[e]) + bf2f(d0[e]) + bf2f(p0[e]);
                float t0 = fmaf(fmaf(v, rsig, nmrs), (&g.x)[e], (&bb.x)[e]);
                t0 = t0 > 0.f ? t0 : __expf(t0) - 1.f;
                acc2e = fmaf(t0, (&w.x)[e], acc2e);
            }
        }
#pragma unroll
        for (int off = 1; off < 16; off <<= 1) acc2e += __shfl_xor(acc2e, off);

        if (fl == 0 && active) {
            const int jb = ii - KWIN < 0 ? 0 : ii - KWIN;
            const int n = rowstart(ii) + (j - jb);
            out[(size_t)b * NC + n] = acc2e + b2v;
            if (b == 0) {
                posout[2 * (size_t)n]     = (float)(ii + 1);
                posout[2 * (size_t)n + 1] = (float)(j + 1);
            }
        }
    }
}

// ---------------------------------------------------------------------------
extern "C" void kernel_launch(void* const* d_in, const int* in_sizes, int n_in,
                              void* d_out, int out_size, void* d_ws, size_t ws_size,
                              hipStream_t stream) {
    const float* h_e     = (const float*)d_in[0];
    const float* h_c     = (const float*)d_in[1];
    const float* h_share = (const float*)d_in[2];
    // d_in[3] = mask (unused)
    const float* pos_W   = (const float*)d_in[4];
    const float* W1      = (const float*)d_in[5];
    const float* b1      = (const float*)d_in[6];
    const float* ln_g    = (const float*)d_in[7];
    const float* ln_b    = (const float*)d_in[8];
    const float* W2      = (const float*)d_in[9];
    const float* b2      = (const float*)d_in[10];

    float* ws     = (float*)d_ws;
    short* prelbf = (short*)ws;
    short* Wb     = (short*)(ws + WB_OFF);

    float* out    = (float*)d_out;
    float* posout = out + BNC;

    prep_kernel<<<115, 256, 0, stream>>>(pos_W, W1, b1, prelbf, Wb);

    fused_kernel<<<NB * NTB, THREADS, 0, stream>>>(
        h_e, h_c, h_share, Wb, prelbf, ln_g, ln_b, W2, b2, out, posout);
}

// Round 7
// 122.646 us; speedup vs baseline: 1.7157x; 1.0115x over previous
//
#include <hip/hip_runtime.h>
#include <hip/hip_bf16.h>
#include <math.h>

// Problem constants
#define L_SEQ   1024
#define NB      8
#define H_DIM   300
#define KWIN    5
#define NREL    11          // 2K+1
#define PDIM    50
#define NC      11234       // band pair count for L=1024, K=5
#define BNC     (NB*NC)     // 89872
#define LN_EPS  1e-5f

#define KPAD    320         // K padded with zeros in [300,320)
#define WKSTR   320         // Wb k-stride (shorts)
#define WNPAD   320         // Wb padded n rows

#define ITILE   32          // i rows per block
#define NTB     32          // i-tiles per batch
#define THREADS 1024        // 16 waves
#define HROWS   42          // hc halo rows: i0-5 .. i0+36
#define XROWS   96          // 0..31 he/Ae (E0,E1), 32..79 hc/Ac (C0,C1,C2;
                            // 74..79 zero), 80..90 Pb, 91 ones, 92..95 zero
#define XSTR    328         // X row stride in shorts
#define NPAIR   (ITILE*NREL)  // 352

// Workspace layout (float offsets)
#define WB_OFF   2048       // prelbf (11*328 shorts = 7216 B) lives at 0
                            // Wb: 2*320*320 shorts = 102400 floats

typedef __attribute__((ext_vector_type(8))) short s16x8;
typedef __attribute__((ext_vector_type(4))) short s16x4;
typedef __attribute__((ext_vector_type(4))) float f32x4;

__device__ __forceinline__ short f2bf(float f) {
    unsigned u = __float_as_uint(f);
    u += 0x7fffu + ((u >> 16) & 1u);
    return (short)(u >> 16);
}
__device__ __forceinline__ float bf2f(short s) {
    return __uint_as_float(((unsigned)(unsigned short)s) << 16);
}

// band row start: first linear index n of row i
__device__ __forceinline__ int rowstart(int i) {
    if (i < 5)     return 6 * i + (i * (i - 1)) / 2;
    if (i <= 1018) return 40 + (i - 5) * 11;
    int d = i - 1019;
    return 11194 + d * 10 - (d * (d - 1)) / 2;
}

// ---------------------------------------------------------------------------
// Kernel 1: prep (unchanged).
__global__ __launch_bounds__(256) void prep_kernel(
    const float* __restrict__ pos_W, const float* __restrict__ W1,
    const float* __restrict__ b1, short* __restrict__ prelbf,
    short* __restrict__ Wb)
{
    if (blockIdx.x < 15) {
        __shared__ float semb[NREL * PDIM];
        for (int t = threadIdx.x; t < NREL * PDIM; t += 256) {
            int r = t / PDIM, d = t % PDIM;
            float acc = 0.f;
#pragma unroll
            for (int r2 = 0; r2 < NREL; ++r2) {
                float cnt = (float)(L_SEQ - abs(r2 - KWIN));
                int dr = r - r2;
                acc += cnt * expf(-(float)(dr * dr)) * pos_W[r2 * PDIM + d];
            }
            semb[t] = acc;
        }
        __syncthreads();
        int t = blockIdx.x * 256 + threadIdx.x;
        if (t < NREL * XSTR) {
            int r = t / XSTR, h = t % XSTR;
            float acc = 0.f;
            if (h < H_DIM) {
                acc = b1[h];
                const float* wrow = W1 + (size_t)h * 650 + 600;
                const float* em = semb + r * PDIM;
#pragma unroll 10
                for (int d = 0; d < PDIM; ++d) acc += wrow[d] * em[d];
            }
            prelbf[t] = (h < H_DIM) ? f2bf(acc) : (short)0;
        }
    } else {
        // 2*320*320 shorts = 25600 s16x8 chunks over 100 blocks
        int c = (blockIdx.x - 15) * 256 + threadIdx.x;
        if (c < 25600) {
            int z   = c / 12800;
            int rem = c - z * 12800;
            int n   = rem / 40;
            int k0  = (rem - n * 40) * 8;
            s16x8 v8 = (s16x8){0,0,0,0,0,0,0,0};
            if (n < H_DIM) {
                const float* base = W1 + (size_t)n * 650 + z * H_DIM;
#pragma unroll
                for (int e = 0; e < 8; ++e) {
                    int k = k0 + e;
                    float v = 0.f;
                    if (k < H_DIM) v = base[k];
                    v8[e] = f2bf(v);
                }
            }
            *(s16x8*)&Wb[(size_t)c * 8] = v8;
        }
    }
}

// ---------------------------------------------------------------------------
// Kernel 2: fused GEMM + Gram + epilogue. Block = (b, i-tile of 32),
// 1024 threads (16 waves), grid 256.
// GEMM window uses ALL 16 waves: wave 12 = concurrent P.P Gram;
// E-half: waves 0..4, 64-col Wb slice each, 2 M-tiles -> 8 chains/kstep;
// C-half: waves 5..11,13..15 (cw 0..9), 32-col slice, 3 M-tiles -> 6 chains.
// Each Wb byte read exactly once (volume floor). Unified regs ~92 (<128
// cliff, m69: wave ceiling halves at 64/128/256). setprio(1) around MFMA.
// NO min-waves launch_bounds (r1-r3: caps -> catastrophic spills).
__global__ __launch_bounds__(THREADS) void fused_kernel(
    const float* __restrict__ h_e, const float* __restrict__ h_c,
    const float* __restrict__ h_share, const short* __restrict__ Wb,
    const short* __restrict__ prelbf,
    const float* __restrict__ ln_g, const float* __restrict__ ln_b,
    const float* __restrict__ W2, const float* __restrict__ b2,
    float* __restrict__ out, float* __restrict__ posout)
{
    __shared__ __align__(16) short X[XROWS * XSTR];   // 62976 B
    __shared__ __align__(16) float GL[9 * 272];       // 9792 B (9 full frags)
    __shared__ __align__(16) float SSeA[32];
    __shared__ __align__(16) float SScA[48];
    __shared__ __align__(16) float SSpA[16];
    __shared__ __align__(16) float SpA[16];
    __shared__ __align__(16) float SG[320];
    __shared__ __align__(16) float SB[320];
    __shared__ __align__(16) float SW[320];

    const int tid = threadIdx.x;
    const int b   = blockIdx.x >> 5;          // 32 i-tiles per batch
    const int i0  = (blockIdx.x & 31) * ITILE;

    // ---- zero-fill: rows 74..79 & 92..95 full width (10*41) + rows 0..73
    // cols [304,328) (74*3) = 632 16B chunks
    for (int t = tid; t < 632; t += THREADS) {
        int row, c;
        if (t < 410) { int rr2 = t / 41; row = rr2 < 6 ? 74 + rr2 : 92 + (rr2 - 6); c = (t % 41) * 8; }
        else         { int u = t - 410; row = u / 3; c = 304 + (u % 3) * 8; }
        *(s16x8*)&X[row * XSTR + c] = (s16x8){0,0,0,0,0,0,0,0};
    }
    // ---- ones row (91): bf16(1.0)=0x3F80 for cols<300, else 0
    for (int t = tid; t < XSTR; t += THREADS)
        X[91 * XSTR + t] = (t < H_DIM) ? (short)0x3F80 : (short)0;
    // ---- Pb rows 80..90: straight copy from prelbf (layout matches)
    for (int t = tid; t < NREL * 41; t += THREADS) {
        int r = t / 41, c = (t % 41) * 8;
        *(s16x8*)&X[(80 + r) * XSTR + c] = *(const s16x8*)(prelbf + r * XSTR + c);
    }
    // ---- LN params to LDS (zero pad to 320)
    if (tid < 320) {
        bool v = tid < H_DIM;
        SG[tid] = v ? ln_g[tid] : 0.f;
        SB[tid] = v ? ln_b[tid] : 0.f;
        SW[tid] = v ? W2[tid]   : 0.f;
    }
    // ---- stage 42 halo rows; h_share read once per row.
    for (int t = tid; t < HROWS * 76; t += THREADS) {
        int s = t / 76, kc = (t % 76) * 4;
        int g = i0 - KWIN + s;
        bool valid = (kc < H_DIM) && (g >= 0) && (g < L_SEQ);
        float4 hs4 = make_float4(0.f,0.f,0.f,0.f), hc4 = hs4;
        size_t off = 0;
        if (valid) {
            off = ((size_t)b * L_SEQ + g) * H_DIM + kc;
            hs4 = *(const float4*)(h_share + off);
            hc4 = *(const float4*)(h_c + off);
        }
        s16x4 vc = { f2bf(hc4.x + hs4.x), f2bf(hc4.y + hs4.y),
                     f2bf(hc4.z + hs4.z), f2bf(hc4.w + hs4.w) };
        *(s16x4*)&X[(32 + s) * XSTR + kc] = vc;
        if (s >= KWIN && s < KWIN + ITILE) {   // he row: g = i0 + (s-5)
            float4 he4 = make_float4(0.f,0.f,0.f,0.f);
            if (valid) he4 = *(const float4*)(h_e + off);
            s16x4 ve = { f2bf(he4.x + hs4.x), f2bf(he4.y + hs4.y),
                         f2bf(he4.z + hs4.z), f2bf(he4.w + hs4.w) };
            *(s16x4*)&X[(s - KWIN) * XSTR + kc] = ve;
        }
    }
    __syncthreads();

    // ---- Main GEMM (15 waves) + PP Gram (wave 12).
    const int wave = tid >> 6, lane = tid & 63;
    const int fr = lane & 15, fq = lane >> 4;

    f32x4 acc[8] = {};

    if (wave == 12) {
        // P.P Gram (rows 80..95): only depends on staged Pb/ones rows.
        f32x4 gp = {};
        for (int k0 = 0; k0 < KPAD; k0 += 32) {
            s16x8 av = *(const s16x8*)&X[(80 + fr) * XSTR + k0 + fq * 8];
            gp = __builtin_amdgcn_mfma_f32_16x16x32_bf16(av, av, gp, 0, 0, 0);
        }
#pragma unroll
        for (int r2 = 0; r2 < 4; ++r2) {
            if (fr == fq * 4 + r2) SSpA[fr] = gp[r2];
            if (fr == 11)          SpA[fq * 4 + r2] = gp[r2];
        }
    } else if (wave < 5) {
        // E-half: wave e owns Wb cols [e*64, e*64+64), M tiles E0,E1.
        const short* wbase = Wb + ((size_t)(wave * 64 + fr)) * WKSTR + fq * 8;
        for (int k0 = 0; k0 < KPAD; k0 += 32) {
            s16x8 bf[4];
#pragma unroll
            for (int nt = 0; nt < 4; ++nt)
                bf[nt] = *(const s16x8*)(wbase + (size_t)nt * 16 * WKSTR + k0);
            s16x8 a0 = *(const s16x8*)&X[fr * XSTR + k0 + fq * 8];
            s16x8 a1 = *(const s16x8*)&X[(16 + fr) * XSTR + k0 + fq * 8];
            __builtin_amdgcn_s_setprio(1);
#pragma unroll
            for (int nt = 0; nt < 4; ++nt) {
                acc[nt]     = __builtin_amdgcn_mfma_f32_16x16x32_bf16(a0, bf[nt], acc[nt], 0, 0, 0);
                acc[4 + nt] = __builtin_amdgcn_mfma_f32_16x16x32_bf16(a1, bf[nt], acc[4 + nt], 0, 0, 0);
            }
            __builtin_amdgcn_s_setprio(0);
        }
    } else {
        // C-half: cw = 0..9 owns Wb cols [cw*32, cw*32+32), M tiles C0,C1,C2.
        const int cw = (wave < 12) ? (wave - 5) : (wave - 6);   // 0..6, 7..9
        const short* wbase = Wb + ((size_t)(WNPAD + cw * 32 + fr)) * WKSTR + fq * 8;
        for (int k0 = 0; k0 < KPAD; k0 += 32) {
            s16x8 bf[2];
#pragma unroll
            for (int nt = 0; nt < 2; ++nt)
                bf[nt] = *(const s16x8*)(wbase + (size_t)nt * 16 * WKSTR + k0);
            s16x8 a0 = *(const s16x8*)&X[(32 + fr) * XSTR + k0 + fq * 8];
            s16x8 a1 = *(const s16x8*)&X[(48 + fr) * XSTR + k0 + fq * 8];
            s16x8 a2 = *(const s16x8*)&X[(64 + fr) * XSTR + k0 + fq * 8];
            __builtin_amdgcn_s_setprio(1);
#pragma unroll
            for (int nt = 0; nt < 2; ++nt) {
                acc[nt]     = __builtin_amdgcn_mfma_f32_16x16x32_bf16(a0, bf[nt], acc[nt], 0, 0, 0);
                acc[2 + nt] = __builtin_amdgcn_mfma_f32_16x16x32_bf16(a1, bf[nt], acc[2 + nt], 0, 0, 0);
                acc[4 + nt] = __builtin_amdgcn_mfma_f32_16x16x32_bf16(a2, bf[nt], acc[4 + nt], 0, 0, 0);
            }
            __builtin_amdgcn_s_setprio(0);
        }
    }
    __syncthreads();   // all waves done reading X he/hc inputs

    // ---- write Ae/Ac into X (bf16). C/D: col within slice +nt*16+fr,
    // row = tile_base + fq*4 + r2. Cols >= 300 compute to 0 (Wb zero cols).
    if (wave != 12) {
        if (wave < 5) {
            const int c0 = wave * 64;
#pragma unroll
            for (int nt = 0; nt < 4; ++nt) {
                const int col = c0 + nt * 16 + fr;
#pragma unroll
                for (int r2 = 0; r2 < 4; ++r2) {
                    X[(fq * 4 + r2) * XSTR + col]      = f2bf(acc[nt][r2]);
                    X[(16 + fq * 4 + r2) * XSTR + col] = f2bf(acc[4 + nt][r2]);
                }
            }
        } else {
            const int cw = (wave < 12) ? (wave - 5) : (wave - 6);
            const int c0 = cw * 32;
#pragma unroll
            for (int nt = 0; nt < 2; ++nt) {
                const int col = c0 + nt * 16 + fr;
#pragma unroll
                for (int m = 0; m < 3; ++m)
#pragma unroll
                    for (int r2 = 0; r2 < 4; ++r2)
                        X[(32 + m * 16 + fq * 4 + r2) * XSTR + col] = f2bf(acc[2 * m + nt][r2]);
            }
        }
    }
    __syncthreads();

    // ---- Gram: the 15 needed fragments over 96 rows (k=320).
    // Tiles: E0=0,E1=16,C0=32,C1=48,C2=64,P=80.
    // waves 0..8 full frags: EC {(0,32),(0,48),(16,48),(16,64)},
    // EP {(0,80),(16,80)}, CP {(32,80),(48,80),(64,80)} -> GL[w].
    // diag (1 job/wave): 9:E0->SSeA, 10:E1->SSeA+16, 11:C0->SScA,
    // 13:C1->SScA+16, 14:C2->SScA+32. (PP by wave 12 earlier.)
    if (wave < 9) {
        int mrow, nrow;
        if (wave < 2)       { mrow = 0;                nrow = 32 + 16 * wave; }
        else if (wave == 2) { mrow = 16;               nrow = 48; }
        else if (wave == 3) { mrow = 16;               nrow = 64; }
        else if (wave < 6)  { mrow = 16 * (wave - 4);  nrow = 80; }
        else                { mrow = 32 + 16 * (wave - 6); nrow = 80; }
        f32x4 ga = {};
        for (int k0 = 0; k0 < KPAD; k0 += 32) {
            s16x8 av = *(const s16x8*)&X[(mrow + fr) * XSTR + k0 + fq * 8];
            s16x8 bv = *(const s16x8*)&X[(nrow + fr) * XSTR + k0 + fq * 8];
            ga = __builtin_amdgcn_mfma_f32_16x16x32_bf16(av, bv, ga, 0, 0, 0);
        }
#pragma unroll
        for (int r2 = 0; r2 < 4; ++r2)
            GL[wave * 272 + (fq * 4 + r2) * 17 + fr] = ga[r2];
    } else if (wave == 9 || wave == 10 || wave == 11 || wave == 13 || wave == 14) {
        int rbase;
        float* dst;
        if (wave == 9)       { rbase = 0;  dst = SSeA; }
        else if (wave == 10) { rbase = 16; dst = SSeA + 16; }
        else if (wave == 11) { rbase = 32; dst = SScA; }
        else if (wave == 13) { rbase = 48; dst = SScA + 16; }
        else                 { rbase = 64; dst = SScA + 32; }
        f32x4 ga = {};
        for (int k0 = 0; k0 < KPAD; k0 += 32) {
            s16x8 av = *(const s16x8*)&X[(rbase + fr) * XSTR + k0 + fq * 8];
            ga = __builtin_amdgcn_mfma_f32_16x16x32_bf16(av, av, ga, 0, 0, 0);
        }
#pragma unroll
        for (int r2 = 0; r2 < 4; ++r2)
            if (fr == fq * 4 + r2) dst[fr] = ga[r2];
    }
    __syncthreads();

    // ---- Epilogue: 1 pair per 16-lane quad, 64 quads, 6 rounds (352 pairs).
    const int quad = lane >> 4, fl = lane & 15;
    const int qq = wave * 4 + quad;            // 0..63
    const float b2v = b2[0];
    const float inv = 1.f / (float)H_DIM;

    for (int round = 0; round < 6; ++round) {
        const int q = round * 64 + qq;          // 0..383
        const int qc = q < NPAIR - 1 ? q : NPAIR - 1;
        const int di = qc / NREL, rr = qc % NREL;
        const int ii = i0 + di, j = ii - KWIN + rr;
        const bool active = (q < NPAIR) && (j >= 0) && (j < L_SEQ);

        const int Et = di >> 4, et = di & 15;
        const int hidx = di + rr;               // 0..41
        const int Ct = hidx >> 4, ct = hidx & 15;
        const int fEC = Et ? (1 + Ct) : Ct;     // (0,32)(0,48)(16,48)(16,64)

        const float Dec = GL[fEC * 272 + et * 17 + ct];
        const float Dep = GL[(4 + Et) * 272 + et * 17 + rr];
        const float Se  = GL[(4 + Et) * 272 + et * 17 + 11];
        const float Dcp = GL[(6 + Ct) * 272 + ct * 17 + rr];
        const float Sc  = GL[(6 + Ct) * 272 + ct * 17 + 11];
        const float SSe = SSeA[di];
        const float SSc = SScA[hidx];
        const float SSp = SSpA[rr];
        const float Sp  = SpA[rr];

        const float mu   = (Se + Sc + Sp) * inv;
        const float ss   = SSe + SSc + SSp + 2.f * (Dec + Dep + Dcp);
        const float rsig = rsqrtf(ss * inv - mu * mu + LN_EPS);
        const float nmrs = -mu * rsig;

        const int ea = di * XSTR;               // Ae row
        const int ca = (32 + hidx) * XSTR;      // Ac row
        const int pa = (80 + rr) * XSTR;        // Pb row

        float acc2e = 0.f;
#pragma unroll
        for (int w5 = 0; w5 < 5; ++w5) {
            const int c = w5 * 64 + fl * 4;     // 0..316, zero-padded
            s16x4 a0 = *(const s16x4*)&X[ea + c];
            s16x4 d0 = *(const s16x4*)&X[ca + c];
            s16x4 p0 = *(const s16x4*)&X[pa + c];
            float4 g  = *(const float4*)&SG[c];
            float4 bb = *(const float4*)&SB[c];
            float4 w  = *(const float4*)&SW[c];
#pragma unroll
            for (int e = 0; e < 4; ++e) {
                float v = bf2f(a0[e]) + bf2f(d0[e]) + bf2f(p0[e]);
                float t0 = fmaf(fmaf(v, rsig, nmrs), (&g.x)[e], (&bb.x)[e]);
                t0 = t0 > 0.f ? t0 : __expf(t0) - 1.f;
                acc2e = fmaf(t0, (&w.x)[e], acc2e);
            }
        }
#pragma unroll
        for (int off = 1; off < 16; off <<= 1) acc2e += __shfl_xor(acc2e, off);

        if (fl == 0 && active) {
            const int jb = ii - KWIN < 0 ? 0 : ii - KWIN;
            const int n = rowstart(ii) + (j - jb);
            out[(size_t)b * NC + n] = acc2e + b2v;
            if (b == 0) {
                posout[2 * (size_t)n]     = (float)(ii + 1);
                posout[2 * (size_t)n + 1] = (float)(j + 1);
            }
        }
    }
}

// ---------------------------------------------------------------------------
extern "C" void kernel_launch(void* const* d_in, const int* in_sizes, int n_in,
                              void* d_out, int out_size, void* d_ws, size_t ws_size,
                              hipStream_t stream) {
    const float* h_e     = (const float*)d_in[0];
    const float* h_c     = (const float*)d_in[1];
    const float* h_share = (const float*)d_in[2];
    // d_in[3] = mask (unused)
    const float* pos_W   = (const float*)d_in[4];
    const float* W1      = (const float*)d_in[5];
    const float* b1      = (const float*)d_in[6];
    const float* ln_g    = (const float*)d_in[7];
    const float* ln_b    = (const float*)d_in[8];
    const float* W2      = (const float*)d_in[9];
    const float* b2      = (const float*)d_in[10];

    float* ws     = (float*)d_ws;
    short* prelbf = (short*)ws;
    short* Wb     = (short*)(ws + WB_OFF);

    float* out    = (float*)d_out;
    float* posout = out + BNC;

    prep_kernel<<<115, 256, 0, stream>>>(pos_W, W1, b1, prelbf, Wb);

    fused_kernel<<<NB * NTB, THREADS, 0, stream>>>(
        h_e, h_c, h_share, Wb, prelbf, ln_g, ln_b, W2, b2, out, posout);
}